// Round 2
// baseline (964.998 us; speedup 1.0000x reference)
//
#include <hip/hip_runtime.h>
#include <hip/hip_bf16.h>

// GPR-GNN forward on MI355X.
// R15: k_prop is ~88% of runtime and bound on the L2-miss/L3 gather path
// (204.8MB/hop gathered from a 12.8MB slab that cannot fit a 4MB per-XCD
// L2 -> ~4.6 TB/s effective). Split the feature dim into 4 phases of
// 64B/row (3.2MB/phase) and pin each phase to one XCD pair via the
// blockIdx%8 round-robin mapping, so each XCD gathers only from an
// L2-resident 3.2MB slab. Layout: pbuf[k][phase][node][16 uints].
// csr read non-temporally (streamed 4x/hop, must not evict the slab).
// k_init/k_combine updated to the phased layout; hid layout unchanged.

#define NFEAT 128
#define HID   256
#define NCLS  40
#define KHOPS 10

typedef __attribute__((ext_vector_type(8))) short short8;
typedef __attribute__((ext_vector_type(4))) float floatx4;

__device__ __forceinline__ float blo(unsigned g) { return __uint_as_float(g << 16); }
__device__ __forceinline__ float bhi(unsigned g) { return __uint_as_float(g & 0xffff0000u); }
__device__ __forceinline__ unsigned f2bf(float x) {          // RNE bf16 -> low 16
  unsigned u = __float_as_uint(x);
  return (u + 0x7fffu + ((u >> 16) & 1u)) >> 16;
}
__device__ __forceinline__ unsigned bpack(float a, float b) {
  return f2bf(a) | (f2bf(b) << 16);
}

// ---- storage probe: int64 values < 2^31 have all-zero odd 32-bit words ----
__global__ void k_detect64(const unsigned int* __restrict__ raw, int* __restrict__ flag) {
  __shared__ int any;
  int t = threadIdx.x;
  if (t == 0) any = 0;
  __syncthreads();
  if (raw[2 * t + 1] != 0u) any = 1;
  __syncthreads();
  if (t == 0) flag[0] = (any == 0) ? 1 : 0;   // 1 => int64 storage
}

__global__ void k_zero(int* __restrict__ p, int n) {
  int i = blockIdx.x * blockDim.x + threadIdx.x;
  if (i < n) p[i] = 0;
}

// 1 edge/thread; stores the atomic's return as this edge's rank within dst.
__global__ void k_count(const int* __restrict__ ei32, const long long* __restrict__ ei64,
                        int E, int N, int* __restrict__ cnt, int* __restrict__ rank,
                        const int* __restrict__ flag) {
  int e = blockIdx.x * blockDim.x + threadIdx.x;
  if (e >= E) return;
  int dst = flag[0] ? (int)ei64[(size_t)E + e] : ei32[(size_t)E + e];
  if ((unsigned)dst < (unsigned)N) rank[e] = atomicAdd(&cnt[dst], 1);
  else rank[e] = -1;
}

// ---- 3-level parallel exclusive scan (tiles of 1024) ----
__global__ __launch_bounds__(256) void k_scan_a(
    const int* __restrict__ cnt, int* __restrict__ bsum, int n) {
  int t = threadIdx.x;
  int base = blockIdx.x * 1024 + t * 4;
  int s = 0;
  if (base + 3 < n) {
    int4 v = *(const int4*)(cnt + base);
    s = v.x + v.y + v.z + v.w;
  } else {
    #pragma unroll
    for (int j = 0; j < 4; ++j) if (base + j < n) s += cnt[base + j];
  }
  #pragma unroll
  for (int off = 1; off < 64; off <<= 1) s += __shfl_xor(s, off);
  __shared__ int ws[4];
  if ((t & 63) == 0) ws[t >> 6] = s;
  __syncthreads();
  if (t == 0) bsum[blockIdx.x] = ws[0] + ws[1] + ws[2] + ws[3];
}

__global__ void k_scan_mid(int* __restrict__ bsum, int* __restrict__ S,
                           int ntiles, int n) {
  int t = threadIdx.x;
  int lane = t & 63, wid = t >> 6;
  int v = (t < ntiles) ? bsum[t] : 0;
  int x = v;
  #pragma unroll
  for (int off = 1; off < 64; off <<= 1) {
    int u = __shfl_up(x, off);
    if (lane >= off) x += u;
  }
  __shared__ int ws[16];
  if (lane == 63) ws[wid] = x;
  __syncthreads();
  if (wid == 0) {
    int s2 = (lane < 16) ? ws[lane] : 0;
    #pragma unroll
    for (int off = 1; off < 16; off <<= 1) {
      int u = __shfl_up(s2, off);
      if (lane >= off) s2 += u;
    }
    if (lane < 16) ws[lane] = s2;
  }
  __syncthreads();
  int woff = wid ? ws[wid - 1] : 0;
  if (t < ntiles) bsum[t] = x - v + woff;   // exclusive tile offsets
  if (t == 0) S[n] = ws[15];                // grand total sentinel
}

// per-tile scan + apply; also emits dinv (counts are in registers here)
__global__ __launch_bounds__(256) void k_scan_c(
    const int* __restrict__ cnt, const int* __restrict__ bsum,
    int* __restrict__ S, float* __restrict__ dinv, int n) {
  int t = threadIdx.x;
  int base = blockIdx.x * 1024 + t * 4;
  int v[4];
  if (base + 3 < n) {
    int4 q = *(const int4*)(cnt + base);
    v[0] = q.x; v[1] = q.y; v[2] = q.z; v[3] = q.w;
  } else {
    #pragma unroll
    for (int j = 0; j < 4; ++j) v[j] = (base + j < n) ? cnt[base + j] : 0;
  }
  int tsum = v[0] + v[1] + v[2] + v[3];
  int lane = t & 63, wv = t >> 6;
  int x = tsum;
  #pragma unroll
  for (int off = 1; off < 64; off <<= 1) {
    int u = __shfl_up(x, off);
    if (lane >= off) x += u;
  }
  __shared__ int ws[4];
  if (lane == 63) ws[wv] = x;
  __syncthreads();
  int woff = 0;
  #pragma unroll
  for (int j = 0; j < 4; ++j) if (j < wv) woff += ws[j];
  int run = x - tsum + woff + bsum[blockIdx.x];
  #pragma unroll
  for (int j = 0; j < 4; ++j) {
    int idx = base + j;
    if (idx < n) {
      S[idx] = run;
      dinv[idx] = rsqrtf((float)(v[j] + 1));
      run += v[j];
    }
  }
}

// atomic-free fill: position = S[dst] + rank[e]; store src only.
__global__ void k_fill(const int* __restrict__ ei32, const long long* __restrict__ ei64,
                       int E, int N, const int* __restrict__ S,
                       const int* __restrict__ rank, int* __restrict__ csr,
                       const int* __restrict__ flag) {
  int e = blockIdx.x * blockDim.x + threadIdx.x;
  if (e >= E) return;
  int r = rank[e];
  if (r < 0) return;
  int src, dst;
  if (flag[0]) { src = (int)ei64[e]; dst = (int)ei64[(size_t)E + e]; }
  else         { src = ei32[e];      dst = ei32[(size_t)E + e]; }
  if ((unsigned)src >= (unsigned)N) return;
  csr[S[dst] + r] = src;
}

// init: p0 = dinv*x, phased layout: p0[(c>>4)*N*16 + n*16 + (c&15)]
__global__ void k_init(const float* __restrict__ x, const float* __restrict__ dinv,
                       unsigned* __restrict__ p0, int N) {
  int i = blockIdx.x * blockDim.x + threadIdx.x;
  if (i >= N * 64) return;
  int n = i >> 6, c = i & 63;
  float2 xv = ((const float2*)x)[i];
  float di = dinv[n];
  p0[(size_t)(c >> 4) * N * 16 + (size_t)n * 16 + (c & 15)] =
      bpack(di * xv.x, di * xv.y);
}

// One wave per (node, phase). Phase = 16 uints = 64B sub-row (3.2MB slab,
// fits one XCD's 4MB L2). blockIdx%8 -> XCD pair -> phase, so each XCD
// only ever gathers from its own phase slab. Lane = e*4+q: 16 edges per
// gather instruction, 2 instructions (32 edges) in flight per iteration.
// csr is streamed non-temporally (no reuse; must not evict the slab).
__global__ __launch_bounds__(256) void k_prop(
    const unsigned* __restrict__ pin, unsigned* __restrict__ pout,
    const int* __restrict__ S, const int* __restrict__ csr,
    const float* __restrict__ dinv, int N) {
  int b = blockIdx.x;
  int xcd = b & 7;
  int phase = xcd >> 1;
  int grp = (b >> 3) * 2 + (xcd & 1);
  int wid = __builtin_amdgcn_readfirstlane(threadIdx.x >> 6);
  int lane = threadIdx.x & 63;
  int node = grp * 4 + wid;
  if (node >= N) return;
  const unsigned* pinp  = pin  + (size_t)phase * N * 16;
  unsigned*       poutp = pout + (size_t)phase * N * 16;
  int q = lane & 3;          // 16B quarter of the 64B sub-row
  int e = lane >> 2;         // edge slot 0..15
  int s = S[node], en = S[node + 1];
  float acc[8] = {0.f, 0.f, 0.f, 0.f, 0.f, 0.f, 0.f, 0.f};
  for (int p = s; p < en; p += 32) {
    uint4 gd[2];
    float wt[2];
    #pragma unroll
    for (int t = 0; t < 2; ++t) {
      int pj = p + t * 16 + e;
      int sidx = __builtin_nontemporal_load(&csr[pj < en ? pj : s]);
      wt[t] = (pj < en) ? 1.f : 0.f;
      gd[t] = *(const uint4*)(pinp + (size_t)sidx * 16 + q * 4);
    }
    #pragma unroll
    for (int t = 0; t < 2; ++t) {
      const unsigned* gu = (const unsigned*)&gd[t];
      #pragma unroll
      for (int u = 0; u < 4; ++u) {
        acc[u * 2]     += wt[t] * blo(gu[u]);
        acc[u * 2 + 1] += wt[t] * bhi(gu[u]);
      }
    }
  }
  #pragma unroll
  for (int u = 0; u < 8; ++u) {              // reduce over 16 edge slots
    acc[u] += __shfl_xor(acc[u], 4);
    acc[u] += __shfl_xor(acc[u], 8);
    acc[u] += __shfl_xor(acc[u], 16);
    acc[u] += __shfl_xor(acc[u], 32);
  }
  if (e == 0) {                              // lanes 0-3 own the epilogue
    float di = dinv[node];
    float dd = di * di;
    uint4 gs = *(const uint4*)(pinp + (size_t)node * 16 + q * 4);
    const unsigned* su = (const unsigned*)&gs;
    #pragma unroll
    for (int u = 0; u < 4; ++u) {
      acc[u * 2]     += blo(su[u]);          // self term: p[i], weight 1
      acc[u * 2 + 1] += bhi(su[u]);
    }
    uint4 pk;                                // p_new = dinv^2 * (sum + self)
    pk.x = bpack(dd * acc[0], dd * acc[1]);
    pk.y = bpack(dd * acc[2], dd * acc[3]);
    pk.z = bpack(dd * acc[4], dd * acc[5]);
    pk.w = bpack(dd * acc[6], dd * acc[7]);
    *(uint4*)(poutp + (size_t)node * 16 + q * 4) = pk;
  }
}

// hid = (sum_k temp[k] * p_k) / dinv over the phased layout. grid.y = phase.
__global__ void k_combine(const unsigned* __restrict__ pbuf,
                          const float* __restrict__ temp,
                          const float* __restrict__ dinv,
                          unsigned* __restrict__ hid, int N) {
  int j = blockIdx.x * blockDim.x + threadIdx.x;   // within-phase storage idx
  int n16 = N * 16;
  if (j >= n16) return;
  int p = blockIdx.y;
  size_t slab = (size_t)N * 64;
  size_t idx = (size_t)p * n16 + j;
  float tL = 0.f, tH = 0.f;
  #pragma unroll
  for (int k = 0; k <= KHOPS; ++k) {         // 11 independent streaming loads
    unsigned v = pbuf[slab * k + idx];
    float tk = temp[k];
    tL += tk * blo(v);
    tH += tk * bhi(v);
  }
  int n = j >> 4, w = j & 15;
  float inv = 1.f / dinv[n];                 // h = p / dinv
  hid[(size_t)n * 64 + p * 16 + w] = bpack(tL * inv, tH * inv);
}

// hidden_bf16 (Mx128) @ W1 (128x256 f32) + b1, relu -> z1 (Mx256 bf16).
__global__ __launch_bounds__(256) void k_gemm1(
    const unsigned short* __restrict__ Ab, const float* __restrict__ W1,
    const float* __restrict__ b1, unsigned short* __restrict__ z1, int M) {
  __shared__ unsigned short As[64][136];    // m-major, k contig, +8 pad
  __shared__ unsigned short Bs[16][128][8]; // [k>>3][n][k&7]: frag = ds_read_b128
  int tid = threadIdx.x;
  int m0 = blockIdx.x * 64;
  int n0 = blockIdx.y * 128;
  for (int idx = tid; idx < 64 * 16; idx += 256) {
    int m = idx >> 4, c = idx & 15;
    int row = m0 + m; if (row >= M) row = M - 1;
    uint4 v = *(const uint4*)(Ab + (size_t)row * NFEAT + c * 8);
    *(uint4*)&As[m][c * 8] = v;
  }
  for (int idx = tid; idx < 128 * 128; idx += 256) {
    int k = idx >> 7, n = idx & 127;
    Bs[k >> 3][n][k & 7] = (unsigned short)f2bf(W1[(size_t)k * HID + n0 + n]);
  }
  __syncthreads();
  int lane = tid & 63;
  int q = lane >> 4, r16 = lane & 15;
  int nw = (tid >> 6) * 32;
  floatx4 acc[4][2] = {};
  #pragma unroll
  for (int step = 0; step < 4; ++step) {
    int k0 = step * 32;
    short8 a[4], b[2];
    #pragma unroll
    for (int i = 0; i < 4; ++i)
      a[i] = *(const short8*)&As[i * 16 + r16][k0 + q * 8];
    #pragma unroll
    for (int j = 0; j < 2; ++j)
      b[j] = *(const short8*)&Bs[step * 4 + q][nw + j * 16 + r16][0];
    #pragma unroll
    for (int i = 0; i < 4; ++i)
      #pragma unroll
      for (int j = 0; j < 2; ++j)
        acc[i][j] = __builtin_amdgcn_mfma_f32_16x16x32_bf16(a[i], b[j], acc[i][j], 0, 0, 0);
  }
  __syncthreads();
  unsigned short* Zs = &As[0][0];
  #pragma unroll
  for (int j = 0; j < 2; ++j) {
    int n = nw + j * 16 + r16;
    float bias = b1[n0 + n];
    #pragma unroll
    for (int i = 0; i < 4; ++i) {
      #pragma unroll
      for (int r = 0; r < 4; ++r) {
        int m = i * 16 + q * 4 + r;
        float v = fmaxf(acc[i][j][r] + bias, 0.f);
        Zs[m * 136 + n] = (unsigned short)f2bf(v);
      }
    }
  }
  __syncthreads();
  for (int idx = tid; idx < 64 * 16; idx += 256) {
    int m = idx >> 4, c = idx & 15;
    int row = m0 + m;
    if (row < M) {
      uint4 v = *(const uint4*)&Zs[m * 136 + c * 8];
      *(uint4*)(z1 + (size_t)row * HID + n0 + c * 8) = v;
    }
  }
}

// W2 (256x40 f32) -> W2t bf16 [48][256] (n-major, k-contig; n>=40 zero-padded)
__global__ void k_w2prep(const float* __restrict__ W2, unsigned short* __restrict__ W2t) {
  int i = blockIdx.x * blockDim.x + threadIdx.x;
  if (i >= 48 * 256) return;
  int n = i >> 8, k = i & 255;
  W2t[n * 256 + k] = (n < NCLS) ? (unsigned short)f2bf(W2[(size_t)k * NCLS + n]) : 0;
}

// z1 (Mx256 bf16) @ W2t + b2 -> log_softmax -> out f32. LDS-free MFMA.
__global__ __launch_bounds__(256) void k_mlp2(
    const unsigned short* __restrict__ z1, const unsigned short* __restrict__ W2t,
    const float* __restrict__ b2, float* __restrict__ out, int N) {
  int tid = threadIdx.x;
  int lane = tid & 63;
  int wv = tid >> 6;
  int node0 = blockIdx.x * 64 + wv * 16;
  int q = lane >> 4, m = lane & 15;
  int arow = node0 + m; if (arow >= N) arow = N - 1;
  const unsigned short* aptr = z1 + (size_t)arow * HID + q * 8;
  const unsigned short* bptr = W2t + (size_t)m * HID + q * 8;   // + j*16*HID
  floatx4 acc[3] = {};
  #pragma unroll
  for (int step = 0; step < 8; ++step) {     // K = 8 x 32
    short8 a = *(const short8*)(aptr + step * 32);
    #pragma unroll
    for (int j = 0; j < 3; ++j) {
      short8 b = *(const short8*)(bptr + (size_t)j * 16 * HID + step * 32);
      acc[j] = __builtin_amdgcn_mfma_f32_16x16x32_bf16(a, b, acc[j], 0, 0, 0);
    }
  }
  int c = m;                                  // class within tile = col = lane&15
  bool v2 = (c < NCLS - 32);                  // c+32 < 40
  float bb0 = b2[c], bb1 = b2[c + 16];
  float bb2 = v2 ? b2[c + 32] : 0.f;
  #pragma unroll
  for (int r = 0; r < 4; ++r) {
    int node = node0 + q * 4 + r;
    float l0 = acc[0][r] + bb0;
    float l1 = acc[1][r] + bb1;
    float l2 = v2 ? (acc[2][r] + bb2) : -3.4e38f;
    float mx = fmaxf(fmaxf(l0, l1), l2);
    #pragma unroll
    for (int off = 1; off < 16; off <<= 1) mx = fmaxf(mx, __shfl_xor(mx, off));
    float sm = __expf(l0 - mx) + __expf(l1 - mx) + (v2 ? __expf(l2 - mx) : 0.f);
    #pragma unroll
    for (int off = 1; off < 16; off <<= 1) sm += __shfl_xor(sm, off);
    float lse = mx + __logf(sm);
    if (node < N) {
      float* op = out + (size_t)node * NCLS + c;
      op[0] = l0 - lse;
      op[16] = l1 - lse;
      if (v2) op[32] = l2 - lse;
    }
  }
}

extern "C" void kernel_launch(void* const* d_in, const int* in_sizes, int n_in,
                              void* d_out, int out_size, void* d_ws, size_t ws_size,
                              hipStream_t stream) {
  const float*     x    = (const float*)d_in[0];
  const int*       ei32 = (const int*)d_in[1];
  const long long* ei64 = (const long long*)d_in[1];
  const float*     temp = (const float*)d_in[2];
  const float*     W1   = (const float*)d_in[3];
  const float*     b1   = (const float*)d_in[4];
  const float*     W2   = (const float*)d_in[5];
  const float*     b2   = (const float*)d_in[6];
  float* out = (float*)d_out;

  int N = in_sizes[0] / NFEAT;   // 50000
  int E = in_sizes[1] / 2;       // 800000

  // workspace carve (~186 MB of the ~268 MB ws)
  char* w = (char*)d_ws;
  auto carve = [&](size_t bytes) -> void* {
    void* p = (void*)w;
    w += (bytes + 255) & ~(size_t)255;
    return p;
  };
  int*      flag      = (int*)     carve(4);
  int*      cnt       = (int*)     carve((size_t)N * 4);
  int*      S         = (int*)     carve(((size_t)N + 1) * 4);
  float*    dinv      = (float*)   carve((size_t)N * 4);
  int*      bsum      = (int*)     carve(1024 * 4);
  unsigned short* W2t = (unsigned short*)carve(48 * 256 * 2);
  int*      rank      = (int*)     carve((size_t)E * 4);
  int*      csr       = (int*)     carve((size_t)E * 4);
  unsigned* pbuf      = (unsigned*)carve((size_t)(KHOPS + 1) * N * 64 * 4); // 11 slabs
  unsigned* hid       = (unsigned*)carve((size_t)N * 64 * 4);   // final hidden bf16
  unsigned short* z1  = (unsigned short*)carve((size_t)N * HID * 2);

  int ntiles = (N + 1023) / 1024;   // 49
  size_t slab = (size_t)N * 64;

  k_detect64<<<1, 256, 0, stream>>>((const unsigned int*)d_in[1], flag);
  k_zero<<<(N + 255) / 256, 256, 0, stream>>>(cnt, N);
  k_count<<<(E + 255) / 256, 256, 0, stream>>>(ei32, ei64, E, N, cnt, rank, flag);
  k_scan_a<<<ntiles, 256, 0, stream>>>(cnt, bsum, N);
  k_scan_mid<<<1, 1024, 0, stream>>>(bsum, S, ntiles, N);
  k_scan_c<<<ntiles, 256, 0, stream>>>(cnt, bsum, S, dinv, N);
  k_fill<<<(E + 255) / 256, 256, 0, stream>>>(ei32, ei64, E, N, S, rank, csr, flag);
  k_init<<<(N * 64 + 255) / 256, 256, 0, stream>>>(x, dinv, pbuf, N);
  k_w2prep<<<48, 256, 0, stream>>>(W2, W2t);

  int ngrp = (N + 3) / 4;                  // 4 nodes per block (per phase)
  int nblk = ((ngrp + 1) / 2) * 8;         // 8 blocks -> 4 phases x 2 groups
  for (int k = 0; k < KHOPS; ++k) {
    k_prop<<<nblk, 256, 0, stream>>>(
        pbuf + slab * k, pbuf + slab * (k + 1), S, csr, dinv, N);
  }
  k_combine<<<dim3((N * 16 + 255) / 256, 4), 256, 0, stream>>>(
      pbuf, temp, dinv, hid, N);

  k_gemm1<<<dim3((N + 63) / 64, 2), 256, 0, stream>>>(
      (const unsigned short*)hid, W1, b1, z1, N);
  k_mlp2<<<(N + 63) / 64, 256, 0, stream>>>(z1, W2t, b2, out, N);
}

// Round 3
// 615.230 us; speedup vs baseline: 1.5685x; 1.5685x over previous
//
#include <hip/hip_runtime.h>
#include <hip/hip_bf16.h>

// GPR-GNN forward on MI355X.
// R16: revert R15's XCD space-partitioning (2x regression: per-XCD working
// set 3.2MB slab + writes + csr > 4MB L2, no residency; paid 2.7x iters).
// New approach: TEMPORAL quartering. CSR is bucketed by source-quarter
// within each dest list (4N-counter build). k_prop keeps the proven R13
// row-major 256B-row gather but iterates quarters innermost, so ALL CUs
// gather from the same 3.2MB source range simultaneously -> every XCD's
// L2 caches the hot quarter independently. csr loads non-temporal.
// Chunk 16->8 edges/iter (quarter lists avg 4 edges) halves clamp waste.

#define NFEAT 128
#define HID   256
#define NCLS  40
#define KHOPS 10

typedef __attribute__((ext_vector_type(8))) short short8;
typedef __attribute__((ext_vector_type(4))) float floatx4;

__device__ __forceinline__ float blo(unsigned g) { return __uint_as_float(g << 16); }
__device__ __forceinline__ float bhi(unsigned g) { return __uint_as_float(g & 0xffff0000u); }
__device__ __forceinline__ unsigned f2bf(float x) {          // RNE bf16 -> low 16
  unsigned u = __float_as_uint(x);
  return (u + 0x7fffu + ((u >> 16) & 1u)) >> 16;
}
__device__ __forceinline__ unsigned bpack(float a, float b) {
  return f2bf(a) | (f2bf(b) << 16);
}

// ---- storage probe: int64 values < 2^31 have all-zero odd 32-bit words ----
__global__ void k_detect64(const unsigned int* __restrict__ raw, int* __restrict__ flag) {
  __shared__ int any;
  int t = threadIdx.x;
  if (t == 0) any = 0;
  __syncthreads();
  if (raw[2 * t + 1] != 0u) any = 1;
  __syncthreads();
  if (t == 0) flag[0] = (any == 0) ? 1 : 0;   // 1 => int64 storage
}

__global__ void k_zero(int* __restrict__ p, int n) {
  int i = blockIdx.x * blockDim.x + threadIdx.x;
  if (i < n) p[i] = 0;
}

// 1 edge/thread; counter bucket = dst*4 + src_quarter. rank = within-bucket pos.
__global__ void k_count4(const int* __restrict__ ei32, const long long* __restrict__ ei64,
                         int E, int N, int qdiv, int* __restrict__ cnt4,
                         int* __restrict__ rank, const int* __restrict__ flag) {
  int e = blockIdx.x * blockDim.x + threadIdx.x;
  if (e >= E) return;
  int src, dst;
  if (flag[0]) { src = (int)ei64[e]; dst = (int)ei64[(size_t)E + e]; }
  else         { src = ei32[e];      dst = ei32[(size_t)E + e]; }
  if ((unsigned)dst < (unsigned)N && (unsigned)src < (unsigned)N) {
    int qtr = src / qdiv;                    // 0..3
    rank[e] = atomicAdd(&cnt4[dst * 4 + qtr], 1);
  } else {
    rank[e] = -1;
  }
}

// ---- 3-level parallel exclusive scan (tiles of 1024) ----
__global__ __launch_bounds__(256) void k_scan_a(
    const int* __restrict__ cnt, int* __restrict__ bsum, int n) {
  int t = threadIdx.x;
  int base = blockIdx.x * 1024 + t * 4;
  int s = 0;
  if (base + 3 < n) {
    int4 v = *(const int4*)(cnt + base);
    s = v.x + v.y + v.z + v.w;
  } else {
    #pragma unroll
    for (int j = 0; j < 4; ++j) if (base + j < n) s += cnt[base + j];
  }
  #pragma unroll
  for (int off = 1; off < 64; off <<= 1) s += __shfl_xor(s, off);
  __shared__ int ws[4];
  if ((t & 63) == 0) ws[t >> 6] = s;
  __syncthreads();
  if (t == 0) bsum[blockIdx.x] = ws[0] + ws[1] + ws[2] + ws[3];
}

__global__ void k_scan_mid(int* __restrict__ bsum, int* __restrict__ S,
                           int ntiles, int n) {
  int t = threadIdx.x;
  int lane = t & 63, wid = t >> 6;
  int v = (t < ntiles) ? bsum[t] : 0;
  int x = v;
  #pragma unroll
  for (int off = 1; off < 64; off <<= 1) {
    int u = __shfl_up(x, off);
    if (lane >= off) x += u;
  }
  __shared__ int ws[16];
  if (lane == 63) ws[wid] = x;
  __syncthreads();
  if (wid == 0) {
    int s2 = (lane < 16) ? ws[lane] : 0;
    #pragma unroll
    for (int off = 1; off < 16; off <<= 1) {
      int u = __shfl_up(s2, off);
      if (lane >= off) s2 += u;
    }
    if (lane < 16) ws[lane] = s2;
  }
  __syncthreads();
  int woff = wid ? ws[wid - 1] : 0;
  if (t < ntiles) bsum[t] = x - v + woff;   // exclusive tile offsets
  if (t == 0) S[n] = ws[15];                // grand total sentinel
}

// per-tile scan + apply
__global__ __launch_bounds__(256) void k_scan_c(
    const int* __restrict__ cnt, const int* __restrict__ bsum,
    int* __restrict__ S, int n) {
  int t = threadIdx.x;
  int base = blockIdx.x * 1024 + t * 4;
  int v[4];
  if (base + 3 < n) {
    int4 q = *(const int4*)(cnt + base);
    v[0] = q.x; v[1] = q.y; v[2] = q.z; v[3] = q.w;
  } else {
    #pragma unroll
    for (int j = 0; j < 4; ++j) v[j] = (base + j < n) ? cnt[base + j] : 0;
  }
  int tsum = v[0] + v[1] + v[2] + v[3];
  int lane = t & 63, wv = t >> 6;
  int x = tsum;
  #pragma unroll
  for (int off = 1; off < 64; off <<= 1) {
    int u = __shfl_up(x, off);
    if (lane >= off) x += u;
  }
  __shared__ int ws[4];
  if (lane == 63) ws[wv] = x;
  __syncthreads();
  int woff = 0;
  #pragma unroll
  for (int j = 0; j < 4; ++j) if (j < wv) woff += ws[j];
  int run = x - tsum + woff + bsum[blockIdx.x];
  #pragma unroll
  for (int j = 0; j < 4; ++j) {
    int idx = base + j;
    if (idx < n) {
      S[idx] = run;
      run += v[j];
    }
  }
}

// dinv from quartered offsets: deg(n) = S4[4n+4]-S4[4n]
__global__ void k_dinv(const int* __restrict__ S4, float* __restrict__ dinv, int N) {
  int n = blockIdx.x * blockDim.x + threadIdx.x;
  if (n >= N) return;
  int d = S4[4 * n + 4] - S4[4 * n];
  dinv[n] = rsqrtf((float)(d + 1));
}

// atomic-free fill: position = S4[dst*4+qtr] + rank[e]; store src only.
__global__ void k_fill(const int* __restrict__ ei32, const long long* __restrict__ ei64,
                       int E, int N, int qdiv, const int* __restrict__ S4,
                       const int* __restrict__ rank, int* __restrict__ csr,
                       const int* __restrict__ flag) {
  int e = blockIdx.x * blockDim.x + threadIdx.x;
  if (e >= E) return;
  int r = rank[e];
  if (r < 0) return;
  int src, dst;
  if (flag[0]) { src = (int)ei64[e]; dst = (int)ei64[(size_t)E + e]; }
  else         { src = ei32[e];      dst = ei32[(size_t)E + e]; }
  int qtr = src / qdiv;
  csr[S4[dst * 4 + qtr] + r] = src;
}

// init: p0 = dinv*x (bf16x2, row-major [node][64])
__global__ void k_init(const float* __restrict__ x, const float* __restrict__ dinv,
                       unsigned* __restrict__ p0, int total64) {
  int i = blockIdx.x * blockDim.x + threadIdx.x;
  if (i >= total64) return;
  float2 xv = ((const float2*)x)[i];
  float di = dinv[i >> 6];
  p0[i] = bpack(di * xv.x, di * xv.y);
}

// One wave per node, R13 row-major 256B-row gather, but edges iterated by
// SOURCE QUARTER (csr bucketed by quarter within dest). All CUs sweep the
// same 3.2MB source range concurrently -> per-XCD L2 holds the hot quarter.
// lane = e*16+g: chunk of 8 edges per iteration (2 x dwordx4 per lane);
// quarter lists avg ~4 edges, so chunk 8 halves clamped-slot waste vs 16.
__global__ __launch_bounds__(256) void k_prop(
    const unsigned* __restrict__ pin, unsigned* __restrict__ pout,
    const int* __restrict__ S4, const int* __restrict__ csr,
    const float* __restrict__ dinv, int N) {
  int wid = __builtin_amdgcn_readfirstlane(threadIdx.x >> 6);
  int lane = threadIdx.x & 63;
  int node = blockIdx.x * 4 + wid;           // uniform (SGPR) per wave
  if (node >= N) return;
  int g = lane & 15;                         // 16B sub-row: uints g*4..g*4+3
  int e = lane >> 4;                         // edge subgroup 0..3
  int4 sA = *(const int4*)(S4 + 4 * node);   // quarter boundaries
  int s4_4 = S4[4 * node + 4];
  int qb[5] = { sA.x, sA.y, sA.z, sA.w, s4_4 };
  float acc[8] = {0.f, 0.f, 0.f, 0.f, 0.f, 0.f, 0.f, 0.f};
  #pragma unroll
  for (int qtr = 0; qtr < 4; ++qtr) {
    int qs = qb[qtr], qe = qb[qtr + 1];
    for (int p = qs; p < qe; p += 8) {       // 8 edges per iteration
      uint4 gd[2];
      float wt[2];
      #pragma unroll
      for (int t = 0; t < 2; ++t) {
        int pj = p + t * 4 + e;
        int sidx = __builtin_nontemporal_load(&csr[pj < qe ? pj : qs]);
        wt[t] = (pj < qe) ? 1.f : 0.f;
        gd[t] = *(const uint4*)(pin + (size_t)sidx * 64 + g * 4);  // 16B of row
      }
      #pragma unroll
      for (int t = 0; t < 2; ++t) {
        const unsigned* gu = (const unsigned*)&gd[t];
        #pragma unroll
        for (int u = 0; u < 4; ++u) {
          acc[u * 2]     += wt[t] * blo(gu[u]);
          acc[u * 2 + 1] += wt[t] * bhi(gu[u]);
        }
      }
    }
  }
  #pragma unroll
  for (int u = 0; u < 8; ++u) {              // reduce over the 4 edge subgroups
    acc[u] += __shfl_xor(acc[u], 16);
    acc[u] += __shfl_xor(acc[u], 32);
  }
  if (e == 0) {                              // lanes 0-15 own the epilogue
    float di = dinv[node];
    float dd = di * di;
    uint4 gs = *(const uint4*)(pin + (size_t)node * 64 + g * 4);
    const unsigned* su = (const unsigned*)&gs;
    #pragma unroll
    for (int u = 0; u < 4; ++u) {
      acc[u * 2]     += blo(su[u]);          // self term: p[i], weight 1
      acc[u * 2 + 1] += bhi(su[u]);
    }
    uint4 pk;                                // p_new = dinv^2 * (sum + self)
    pk.x = bpack(dd * acc[0], dd * acc[1]);
    pk.y = bpack(dd * acc[2], dd * acc[3]);
    pk.z = bpack(dd * acc[4], dd * acc[5]);
    pk.w = bpack(dd * acc[6], dd * acc[7]);
    *(uint4*)(pout + (size_t)node * 64 + g * 4) = pk;
  }
}

// hid = (sum_k temp[k] * p_k) / dinv, streamed over all 11 slabs. bf16 out.
__global__ void k_combine(const unsigned* __restrict__ pbuf,
                          const float* __restrict__ temp,
                          const float* __restrict__ dinv,
                          unsigned* __restrict__ hid, int N) {
  int i = blockIdx.x * blockDim.x + threadIdx.x;
  int total = N * 64;
  if (i >= total) return;
  size_t slab = (size_t)total;
  float tL = 0.f, tH = 0.f;
  #pragma unroll
  for (int k = 0; k <= KHOPS; ++k) {         // 11 independent streaming loads
    unsigned v = pbuf[slab * k + i];
    float tk = temp[k];
    tL += tk * blo(v);
    tH += tk * bhi(v);
  }
  float inv = 1.f / dinv[i >> 6];            // h = p / dinv
  hid[i] = bpack(tL * inv, tH * inv);
}

// hidden_bf16 (Mx128) @ W1 (128x256 f32) + b1, relu -> z1 (Mx256 bf16).
__global__ __launch_bounds__(256) void k_gemm1(
    const unsigned short* __restrict__ Ab, const float* __restrict__ W1,
    const float* __restrict__ b1, unsigned short* __restrict__ z1, int M) {
  __shared__ unsigned short As[64][136];    // m-major, k contig, +8 pad
  __shared__ unsigned short Bs[16][128][8]; // [k>>3][n][k&7]: frag = ds_read_b128
  int tid = threadIdx.x;
  int m0 = blockIdx.x * 64;
  int n0 = blockIdx.y * 128;
  for (int idx = tid; idx < 64 * 16; idx += 256) {
    int m = idx >> 4, c = idx & 15;
    int row = m0 + m; if (row >= M) row = M - 1;
    uint4 v = *(const uint4*)(Ab + (size_t)row * NFEAT + c * 8);
    *(uint4*)&As[m][c * 8] = v;
  }
  for (int idx = tid; idx < 128 * 128; idx += 256) {
    int k = idx >> 7, n = idx & 127;
    Bs[k >> 3][n][k & 7] = (unsigned short)f2bf(W1[(size_t)k * HID + n0 + n]);
  }
  __syncthreads();
  int lane = tid & 63;
  int q = lane >> 4, r16 = lane & 15;
  int nw = (tid >> 6) * 32;
  floatx4 acc[4][2] = {};
  #pragma unroll
  for (int step = 0; step < 4; ++step) {
    int k0 = step * 32;
    short8 a[4], b[2];
    #pragma unroll
    for (int i = 0; i < 4; ++i)
      a[i] = *(const short8*)&As[i * 16 + r16][k0 + q * 8];
    #pragma unroll
    for (int j = 0; j < 2; ++j)
      b[j] = *(const short8*)&Bs[step * 4 + q][nw + j * 16 + r16][0];
    #pragma unroll
    for (int i = 0; i < 4; ++i)
      #pragma unroll
      for (int j = 0; j < 2; ++j)
        acc[i][j] = __builtin_amdgcn_mfma_f32_16x16x32_bf16(a[i], b[j], acc[i][j], 0, 0, 0);
  }
  __syncthreads();
  unsigned short* Zs = &As[0][0];
  #pragma unroll
  for (int j = 0; j < 2; ++j) {
    int n = nw + j * 16 + r16;
    float bias = b1[n0 + n];
    #pragma unroll
    for (int i = 0; i < 4; ++i) {
      #pragma unroll
      for (int r = 0; r < 4; ++r) {
        int m = i * 16 + q * 4 + r;
        float v = fmaxf(acc[i][j][r] + bias, 0.f);
        Zs[m * 136 + n] = (unsigned short)f2bf(v);
      }
    }
  }
  __syncthreads();
  for (int idx = tid; idx < 64 * 16; idx += 256) {
    int m = idx >> 4, c = idx & 15;
    int row = m0 + m;
    if (row < M) {
      uint4 v = *(const uint4*)&Zs[m * 136 + c * 8];
      *(uint4*)(z1 + (size_t)row * HID + n0 + c * 8) = v;
    }
  }
}

// W2 (256x40 f32) -> W2t bf16 [48][256] (n-major, k-contig; n>=40 zero-padded)
__global__ void k_w2prep(const float* __restrict__ W2, unsigned short* __restrict__ W2t) {
  int i = blockIdx.x * blockDim.x + threadIdx.x;
  if (i >= 48 * 256) return;
  int n = i >> 8, k = i & 255;
  W2t[n * 256 + k] = (n < NCLS) ? (unsigned short)f2bf(W2[(size_t)k * NCLS + n]) : 0;
}

// z1 (Mx256 bf16) @ W2t + b2 -> log_softmax -> out f32. LDS-free MFMA.
__global__ __launch_bounds__(256) void k_mlp2(
    const unsigned short* __restrict__ z1, const unsigned short* __restrict__ W2t,
    const float* __restrict__ b2, float* __restrict__ out, int N) {
  int tid = threadIdx.x;
  int lane = tid & 63;
  int wv = tid >> 6;
  int node0 = blockIdx.x * 64 + wv * 16;
  int q = lane >> 4, m = lane & 15;
  int arow = node0 + m; if (arow >= N) arow = N - 1;
  const unsigned short* aptr = z1 + (size_t)arow * HID + q * 8;
  const unsigned short* bptr = W2t + (size_t)m * HID + q * 8;   // + j*16*HID
  floatx4 acc[3] = {};
  #pragma unroll
  for (int step = 0; step < 8; ++step) {     // K = 8 x 32
    short8 a = *(const short8*)(aptr + step * 32);
    #pragma unroll
    for (int j = 0; j < 3; ++j) {
      short8 b = *(const short8*)(bptr + (size_t)j * 16 * HID + step * 32);
      acc[j] = __builtin_amdgcn_mfma_f32_16x16x32_bf16(a, b, acc[j], 0, 0, 0);
    }
  }
  int c = m;                                  // class within tile = col = lane&15
  bool v2 = (c < NCLS - 32);                  // c+32 < 40
  float bb0 = b2[c], bb1 = b2[c + 16];
  float bb2 = v2 ? b2[c + 32] : 0.f;
  #pragma unroll
  for (int r = 0; r < 4; ++r) {
    int node = node0 + q * 4 + r;
    float l0 = acc[0][r] + bb0;
    float l1 = acc[1][r] + bb1;
    float l2 = v2 ? (acc[2][r] + bb2) : -3.4e38f;
    float mx = fmaxf(fmaxf(l0, l1), l2);
    #pragma unroll
    for (int off = 1; off < 16; off <<= 1) mx = fmaxf(mx, __shfl_xor(mx, off));
    float sm = __expf(l0 - mx) + __expf(l1 - mx) + (v2 ? __expf(l2 - mx) : 0.f);
    #pragma unroll
    for (int off = 1; off < 16; off <<= 1) sm += __shfl_xor(sm, off);
    float lse = mx + __logf(sm);
    if (node < N) {
      float* op = out + (size_t)node * NCLS + c;
      op[0] = l0 - lse;
      op[16] = l1 - lse;
      if (v2) op[32] = l2 - lse;
    }
  }
}

extern "C" void kernel_launch(void* const* d_in, const int* in_sizes, int n_in,
                              void* d_out, int out_size, void* d_ws, size_t ws_size,
                              hipStream_t stream) {
  const float*     x    = (const float*)d_in[0];
  const int*       ei32 = (const int*)d_in[1];
  const long long* ei64 = (const long long*)d_in[1];
  const float*     temp = (const float*)d_in[2];
  const float*     W1   = (const float*)d_in[3];
  const float*     b1   = (const float*)d_in[4];
  const float*     W2   = (const float*)d_in[5];
  const float*     b2   = (const float*)d_in[6];
  float* out = (float*)d_out;

  int N = in_sizes[0] / NFEAT;   // 50000
  int E = in_sizes[1] / 2;       // 800000
  int qdiv = (N + 3) / 4;        // source-quarter width

  // workspace carve
  char* w = (char*)d_ws;
  auto carve = [&](size_t bytes) -> void* {
    void* p = (void*)w;
    w += (bytes + 255) & ~(size_t)255;
    return p;
  };
  int*      flag      = (int*)     carve(4);
  int*      cnt4      = (int*)     carve((size_t)N * 4 * 4);       // 4N counters
  int*      S4        = (int*)     carve(((size_t)N * 4 + 1) * 4); // 4N+1 offsets
  float*    dinv      = (float*)   carve((size_t)N * 4);
  int*      bsum      = (int*)     carve(1024 * 4);
  unsigned short* W2t = (unsigned short*)carve(48 * 256 * 2);
  int*      rank      = (int*)     carve((size_t)E * 4);
  int*      csr       = (int*)     carve((size_t)E * 4);
  unsigned* pbuf      = (unsigned*)carve((size_t)(KHOPS + 1) * N * 64 * 4); // 11 slabs
  unsigned* hid       = (unsigned*)carve((size_t)N * 64 * 4);   // final hidden bf16
  unsigned short* z1  = (unsigned short*)carve((size_t)N * HID * 2);

  int n4 = N * 4;
  int ntiles4 = (n4 + 1023) / 1024;   // 196
  size_t slab = (size_t)N * 64;

  k_detect64<<<1, 256, 0, stream>>>((const unsigned int*)d_in[1], flag);
  k_zero<<<(n4 + 255) / 256, 256, 0, stream>>>(cnt4, n4);
  k_count4<<<(E + 255) / 256, 256, 0, stream>>>(ei32, ei64, E, N, qdiv, cnt4, rank, flag);
  k_scan_a<<<ntiles4, 256, 0, stream>>>(cnt4, bsum, n4);
  k_scan_mid<<<1, 1024, 0, stream>>>(bsum, S4, ntiles4, n4);
  k_scan_c<<<ntiles4, 256, 0, stream>>>(cnt4, bsum, S4, n4);
  k_dinv<<<(N + 255) / 256, 256, 0, stream>>>(S4, dinv, N);
  k_fill<<<(E + 255) / 256, 256, 0, stream>>>(ei32, ei64, E, N, qdiv, S4, rank, csr, flag);
  k_init<<<(N * 64 + 255) / 256, 256, 0, stream>>>(x, dinv, pbuf, N * 64);
  k_w2prep<<<48, 256, 0, stream>>>(W2, W2t);

  for (int k = 0; k < KHOPS; ++k) {
    k_prop<<<(N + 3) / 4, 256, 0, stream>>>(
        pbuf + slab * k, pbuf + slab * (k + 1), S4, csr, dinv, N);
  }
  k_combine<<<(N * 64 + 255) / 256, 256, 0, stream>>>(pbuf, temp, dinv, hid, N);

  k_gemm1<<<dim3((N + 63) / 64, 2), 256, 0, stream>>>(
      (const unsigned short*)hid, W1, b1, z1, N);
  k_mlp2<<<(N + 63) / 64, 256, 0, stream>>>(z1, W2t, b2, out, N);
}

// Round 4
// 575.951 us; speedup vs baseline: 1.6755x; 1.0682x over previous
//
#include <hip/hip_runtime.h>
#include <hip/hip_bf16.h>

// GPR-GNN forward on MI355X.
// R17: revert to the proven R13 structure (497.6us). Three rounds of
// locality engineering established that k_prop's random 256B-row gather
// runs at a BALANCED dual-path roofline ~4.8TB/s: ~120MB/hop from per-XCD
// L2 (~2.8TB/s cap, proven by R15's all-L2 82us) + ~86MB/hop via the
// L3/IF path (~2.0TB/s). Forcing locality either way unbalances and
// loses. Remaining safe shavings only:
//  (1) wave-uniform tail guard in k_prop: skip gather instrs fully past
//      en (Poisson-16 degrees -> ~1.44x issue waste -> ~1.1x).
//  (2) non-temporal csr loads: keep the 12.8MB/hop csr stream from
//      evicting hot p-rows in L2.

#define NFEAT 128
#define HID   256
#define NCLS  40
#define KHOPS 10

typedef __attribute__((ext_vector_type(8))) short short8;
typedef __attribute__((ext_vector_type(4))) float floatx4;

__device__ __forceinline__ float blo(unsigned g) { return __uint_as_float(g << 16); }
__device__ __forceinline__ float bhi(unsigned g) { return __uint_as_float(g & 0xffff0000u); }
__device__ __forceinline__ unsigned f2bf(float x) {          // RNE bf16 -> low 16
  unsigned u = __float_as_uint(x);
  return (u + 0x7fffu + ((u >> 16) & 1u)) >> 16;
}
__device__ __forceinline__ unsigned bpack(float a, float b) {
  return f2bf(a) | (f2bf(b) << 16);
}

// ---- storage probe: int64 values < 2^31 have all-zero odd 32-bit words ----
__global__ void k_detect64(const unsigned int* __restrict__ raw, int* __restrict__ flag) {
  __shared__ int any;
  int t = threadIdx.x;
  if (t == 0) any = 0;
  __syncthreads();
  if (raw[2 * t + 1] != 0u) any = 1;
  __syncthreads();
  if (t == 0) flag[0] = (any == 0) ? 1 : 0;   // 1 => int64 storage
}

__global__ void k_zero(int* __restrict__ p, int n) {
  int i = blockIdx.x * blockDim.x + threadIdx.x;
  if (i < n) p[i] = 0;
}

// 1 edge/thread; stores the atomic's return as this edge's rank within dst.
__global__ void k_count(const int* __restrict__ ei32, const long long* __restrict__ ei64,
                        int E, int N, int* __restrict__ cnt, int* __restrict__ rank,
                        const int* __restrict__ flag) {
  int e = blockIdx.x * blockDim.x + threadIdx.x;
  if (e >= E) return;
  int dst = flag[0] ? (int)ei64[(size_t)E + e] : ei32[(size_t)E + e];
  if ((unsigned)dst < (unsigned)N) rank[e] = atomicAdd(&cnt[dst], 1);
  else rank[e] = -1;
}

// ---- 3-level parallel exclusive scan (tiles of 1024) ----
__global__ __launch_bounds__(256) void k_scan_a(
    const int* __restrict__ cnt, int* __restrict__ bsum, int n) {
  int t = threadIdx.x;
  int base = blockIdx.x * 1024 + t * 4;
  int s = 0;
  if (base + 3 < n) {
    int4 v = *(const int4*)(cnt + base);
    s = v.x + v.y + v.z + v.w;
  } else {
    #pragma unroll
    for (int j = 0; j < 4; ++j) if (base + j < n) s += cnt[base + j];
  }
  #pragma unroll
  for (int off = 1; off < 64; off <<= 1) s += __shfl_xor(s, off);
  __shared__ int ws[4];
  if ((t & 63) == 0) ws[t >> 6] = s;
  __syncthreads();
  if (t == 0) bsum[blockIdx.x] = ws[0] + ws[1] + ws[2] + ws[3];
}

__global__ void k_scan_mid(int* __restrict__ bsum, int* __restrict__ S,
                           int ntiles, int n) {
  int t = threadIdx.x;
  int lane = t & 63, wid = t >> 6;
  int v = (t < ntiles) ? bsum[t] : 0;
  int x = v;
  #pragma unroll
  for (int off = 1; off < 64; off <<= 1) {
    int u = __shfl_up(x, off);
    if (lane >= off) x += u;
  }
  __shared__ int ws[16];
  if (lane == 63) ws[wid] = x;
  __syncthreads();
  if (wid == 0) {
    int s2 = (lane < 16) ? ws[lane] : 0;
    #pragma unroll
    for (int off = 1; off < 16; off <<= 1) {
      int u = __shfl_up(s2, off);
      if (lane >= off) s2 += u;
    }
    if (lane < 16) ws[lane] = s2;
  }
  __syncthreads();
  int woff = wid ? ws[wid - 1] : 0;
  if (t < ntiles) bsum[t] = x - v + woff;   // exclusive tile offsets
  if (t == 0) S[n] = ws[15];                // grand total sentinel
}

// per-tile scan + apply; also emits dinv (counts are in registers here)
__global__ __launch_bounds__(256) void k_scan_c(
    const int* __restrict__ cnt, const int* __restrict__ bsum,
    int* __restrict__ S, float* __restrict__ dinv, int n) {
  int t = threadIdx.x;
  int base = blockIdx.x * 1024 + t * 4;
  int v[4];
  if (base + 3 < n) {
    int4 q = *(const int4*)(cnt + base);
    v[0] = q.x; v[1] = q.y; v[2] = q.z; v[3] = q.w;
  } else {
    #pragma unroll
    for (int j = 0; j < 4; ++j) v[j] = (base + j < n) ? cnt[base + j] : 0;
  }
  int tsum = v[0] + v[1] + v[2] + v[3];
  int lane = t & 63, wv = t >> 6;
  int x = tsum;
  #pragma unroll
  for (int off = 1; off < 64; off <<= 1) {
    int u = __shfl_up(x, off);
    if (lane >= off) x += u;
  }
  __shared__ int ws[4];
  if (lane == 63) ws[wv] = x;
  __syncthreads();
  int woff = 0;
  #pragma unroll
  for (int j = 0; j < 4; ++j) if (j < wv) woff += ws[j];
  int run = x - tsum + woff + bsum[blockIdx.x];
  #pragma unroll
  for (int j = 0; j < 4; ++j) {
    int idx = base + j;
    if (idx < n) {
      S[idx] = run;
      dinv[idx] = rsqrtf((float)(v[j] + 1));
      run += v[j];
    }
  }
}

// atomic-free fill: position = S[dst] + rank[e]; store src only.
__global__ void k_fill(const int* __restrict__ ei32, const long long* __restrict__ ei64,
                       int E, int N, const int* __restrict__ S,
                       const int* __restrict__ rank, int* __restrict__ csr,
                       const int* __restrict__ flag) {
  int e = blockIdx.x * blockDim.x + threadIdx.x;
  if (e >= E) return;
  int r = rank[e];
  if (r < 0) return;
  int src, dst;
  if (flag[0]) { src = (int)ei64[e]; dst = (int)ei64[(size_t)E + e]; }
  else         { src = ei32[e];      dst = ei32[(size_t)E + e]; }
  if ((unsigned)src >= (unsigned)N) return;
  csr[S[dst] + r] = src;
}

// init: p0 = dinv*x (bf16x2, row-major [node][64])
__global__ void k_init(const float* __restrict__ x, const float* __restrict__ dinv,
                       unsigned* __restrict__ p0, int total64) {
  int i = blockIdx.x * blockDim.x + threadIdx.x;
  if (i >= total64) return;
  float2 xv = ((const float2*)x)[i];
  float di = dinv[i >> 6];
  p0[i] = bpack(di * xv.x, di * xv.y);
}

// One wave per node. lane = e*16+g: 4 edges per dwordx4 gather instruction,
// 16 edges in flight. p buffers absorb the symmetric normalization, so the
// gather weight is 1 (tail mask only); p_new = dinv^2 * (sum + p_self).
// R17: wave-uniform skip of gather instrs fully past en (issue-waste
// 1.44x -> ~1.1x); csr loads non-temporal (pure stream, keep L2 for rows).
__global__ __launch_bounds__(256) void k_prop(
    const unsigned* __restrict__ pin, unsigned* __restrict__ pout,
    const int* __restrict__ S, const int* __restrict__ csr,
    const float* __restrict__ dinv, int N) {
  int wid = __builtin_amdgcn_readfirstlane(threadIdx.x >> 6);
  int lane = threadIdx.x & 63;
  int node = blockIdx.x * 4 + wid;           // uniform (SGPR) per wave
  if (node >= N) return;
  int g = lane & 15;                         // 16B sub-row: uints g*4..g*4+3
  int e = lane >> 4;                         // edge subgroup 0..3
  int s = S[node], en = S[node + 1];
  float acc[8] = {0.f, 0.f, 0.f, 0.f, 0.f, 0.f, 0.f, 0.f};
  for (int p = s; p < en; p += 16) {
    uint4 gd[4];
    float wt[4];
    #pragma unroll
    for (int t = 0; t < 4; ++t) {
      int pbase = p + t * 4;                 // wave-uniform
      if (pbase < en) {                      // uniform guard: s_cbranch
        int pj = pbase + e;
        int sidx = __builtin_nontemporal_load(&csr[pj < en ? pj : s]);
        wt[t] = (pj < en) ? 1.f : 0.f;
        gd[t] = *(const uint4*)(pin + (size_t)sidx * 64 + g * 4);  // 16B of row
      } else {
        wt[t] = 0.f;
        gd[t].x = 0u; gd[t].y = 0u; gd[t].z = 0u; gd[t].w = 0u;
      }
    }
    #pragma unroll
    for (int t = 0; t < 4; ++t) {
      const unsigned* gu = (const unsigned*)&gd[t];
      #pragma unroll
      for (int u = 0; u < 4; ++u) {
        acc[u * 2]     += wt[t] * blo(gu[u]);
        acc[u * 2 + 1] += wt[t] * bhi(gu[u]);
      }
    }
  }
  #pragma unroll
  for (int u = 0; u < 8; ++u) {              // reduce over the 4 edge subgroups
    acc[u] += __shfl_xor(acc[u], 16);
    acc[u] += __shfl_xor(acc[u], 32);
  }
  if (e == 0) {                              // lanes 0-15 own the epilogue
    float di = dinv[node];
    float dd = di * di;
    uint4 gs = *(const uint4*)(pin + (size_t)node * 64 + g * 4);
    const unsigned* su = (const unsigned*)&gs;
    #pragma unroll
    for (int u = 0; u < 4; ++u) {
      acc[u * 2]     += blo(su[u]);          // self term: p[i], weight 1
      acc[u * 2 + 1] += bhi(su[u]);
    }
    uint4 pk;                                // p_new = dinv^2 * (sum + self)
    pk.x = bpack(dd * acc[0], dd * acc[1]);
    pk.y = bpack(dd * acc[2], dd * acc[3]);
    pk.z = bpack(dd * acc[4], dd * acc[5]);
    pk.w = bpack(dd * acc[6], dd * acc[7]);
    *(uint4*)(pout + (size_t)node * 64 + g * 4) = pk;
  }
}

// hid = (sum_k temp[k] * p_k) / dinv, streamed over all 11 slabs. bf16 out.
__global__ void k_combine(const unsigned* __restrict__ pbuf,
                          const float* __restrict__ temp,
                          const float* __restrict__ dinv,
                          unsigned* __restrict__ hid, int N) {
  int i = blockIdx.x * blockDim.x + threadIdx.x;
  int total = N * 64;
  if (i >= total) return;
  size_t slab = (size_t)total;
  float tL = 0.f, tH = 0.f;
  #pragma unroll
  for (int k = 0; k <= KHOPS; ++k) {         // 11 independent streaming loads
    unsigned v = pbuf[slab * k + i];
    float tk = temp[k];
    tL += tk * blo(v);
    tH += tk * bhi(v);
  }
  float inv = 1.f / dinv[i >> 6];            // h = p / dinv
  hid[i] = bpack(tL * inv, tH * inv);
}

// hidden_bf16 (Mx128) @ W1 (128x256 f32) + b1, relu -> z1 (Mx256 bf16).
__global__ __launch_bounds__(256) void k_gemm1(
    const unsigned short* __restrict__ Ab, const float* __restrict__ W1,
    const float* __restrict__ b1, unsigned short* __restrict__ z1, int M) {
  __shared__ unsigned short As[64][136];    // m-major, k contig, +8 pad
  __shared__ unsigned short Bs[16][128][8]; // [k>>3][n][k&7]: frag = ds_read_b128
  int tid = threadIdx.x;
  int m0 = blockIdx.x * 64;
  int n0 = blockIdx.y * 128;
  for (int idx = tid; idx < 64 * 16; idx += 256) {
    int m = idx >> 4, c = idx & 15;
    int row = m0 + m; if (row >= M) row = M - 1;
    uint4 v = *(const uint4*)(Ab + (size_t)row * NFEAT + c * 8);
    *(uint4*)&As[m][c * 8] = v;
  }
  for (int idx = tid; idx < 128 * 128; idx += 256) {
    int k = idx >> 7, n = idx & 127;
    Bs[k >> 3][n][k & 7] = (unsigned short)f2bf(W1[(size_t)k * HID + n0 + n]);
  }
  __syncthreads();
  int lane = tid & 63;
  int q = lane >> 4, r16 = lane & 15;
  int nw = (tid >> 6) * 32;
  floatx4 acc[4][2] = {};
  #pragma unroll
  for (int step = 0; step < 4; ++step) {
    int k0 = step * 32;
    short8 a[4], b[2];
    #pragma unroll
    for (int i = 0; i < 4; ++i)
      a[i] = *(const short8*)&As[i * 16 + r16][k0 + q * 8];
    #pragma unroll
    for (int j = 0; j < 2; ++j)
      b[j] = *(const short8*)&Bs[step * 4 + q][nw + j * 16 + r16][0];
    #pragma unroll
    for (int i = 0; i < 4; ++i)
      #pragma unroll
      for (int j = 0; j < 2; ++j)
        acc[i][j] = __builtin_amdgcn_mfma_f32_16x16x32_bf16(a[i], b[j], acc[i][j], 0, 0, 0);
  }
  __syncthreads();
  unsigned short* Zs = &As[0][0];
  #pragma unroll
  for (int j = 0; j < 2; ++j) {
    int n = nw + j * 16 + r16;
    float bias = b1[n0 + n];
    #pragma unroll
    for (int i = 0; i < 4; ++i) {
      #pragma unroll
      for (int r = 0; r < 4; ++r) {
        int m = i * 16 + q * 4 + r;
        float v = fmaxf(acc[i][j][r] + bias, 0.f);
        Zs[m * 136 + n] = (unsigned short)f2bf(v);
      }
    }
  }
  __syncthreads();
  for (int idx = tid; idx < 64 * 16; idx += 256) {
    int m = idx >> 4, c = idx & 15;
    int row = m0 + m;
    if (row < M) {
      uint4 v = *(const uint4*)&Zs[m * 136 + c * 8];
      *(uint4*)(z1 + (size_t)row * HID + n0 + c * 8) = v;
    }
  }
}

// W2 (256x40 f32) -> W2t bf16 [48][256] (n-major, k-contig; n>=40 zero-padded)
__global__ void k_w2prep(const float* __restrict__ W2, unsigned short* __restrict__ W2t) {
  int i = blockIdx.x * blockDim.x + threadIdx.x;
  if (i >= 48 * 256) return;
  int n = i >> 8, k = i & 255;
  W2t[n * 256 + k] = (n < NCLS) ? (unsigned short)f2bf(W2[(size_t)k * NCLS + n]) : 0;
}

// z1 (Mx256 bf16) @ W2t + b2 -> log_softmax -> out f32. LDS-free MFMA.
__global__ __launch_bounds__(256) void k_mlp2(
    const unsigned short* __restrict__ z1, const unsigned short* __restrict__ W2t,
    const float* __restrict__ b2, float* __restrict__ out, int N) {
  int tid = threadIdx.x;
  int lane = tid & 63;
  int wv = tid >> 6;
  int node0 = blockIdx.x * 64 + wv * 16;
  int q = lane >> 4, m = lane & 15;
  int arow = node0 + m; if (arow >= N) arow = N - 1;
  const unsigned short* aptr = z1 + (size_t)arow * HID + q * 8;
  const unsigned short* bptr = W2t + (size_t)m * HID + q * 8;   // + j*16*HID
  floatx4 acc[3] = {};
  #pragma unroll
  for (int step = 0; step < 8; ++step) {     // K = 8 x 32
    short8 a = *(const short8*)(aptr + step * 32);
    #pragma unroll
    for (int j = 0; j < 3; ++j) {
      short8 b = *(const short8*)(bptr + (size_t)j * 16 * HID + step * 32);
      acc[j] = __builtin_amdgcn_mfma_f32_16x16x32_bf16(a, b, acc[j], 0, 0, 0);
    }
  }
  int c = m;                                  // class within tile = col = lane&15
  bool v2 = (c < NCLS - 32);                  // c+32 < 40
  float bb0 = b2[c], bb1 = b2[c + 16];
  float bb2 = v2 ? b2[c + 32] : 0.f;
  #pragma unroll
  for (int r = 0; r < 4; ++r) {
    int node = node0 + q * 4 + r;
    float l0 = acc[0][r] + bb0;
    float l1 = acc[1][r] + bb1;
    float l2 = v2 ? (acc[2][r] + bb2) : -3.4e38f;
    float mx = fmaxf(fmaxf(l0, l1), l2);
    #pragma unroll
    for (int off = 1; off < 16; off <<= 1) mx = fmaxf(mx, __shfl_xor(mx, off));
    float sm = __expf(l0 - mx) + __expf(l1 - mx) + (v2 ? __expf(l2 - mx) : 0.f);
    #pragma unroll
    for (int off = 1; off < 16; off <<= 1) sm += __shfl_xor(sm, off);
    float lse = mx + __logf(sm);
    if (node < N) {
      float* op = out + (size_t)node * NCLS + c;
      op[0] = l0 - lse;
      op[16] = l1 - lse;
      if (v2) op[32] = l2 - lse;
    }
  }
}

extern "C" void kernel_launch(void* const* d_in, const int* in_sizes, int n_in,
                              void* d_out, int out_size, void* d_ws, size_t ws_size,
                              hipStream_t stream) {
  const float*     x    = (const float*)d_in[0];
  const int*       ei32 = (const int*)d_in[1];
  const long long* ei64 = (const long long*)d_in[1];
  const float*     temp = (const float*)d_in[2];
  const float*     W1   = (const float*)d_in[3];
  const float*     b1   = (const float*)d_in[4];
  const float*     W2   = (const float*)d_in[5];
  const float*     b2   = (const float*)d_in[6];
  float* out = (float*)d_out;

  int N = in_sizes[0] / NFEAT;   // 50000
  int E = in_sizes[1] / 2;       // 800000

  // workspace carve (~186 MB of the ~268 MB ws)
  char* w = (char*)d_ws;
  auto carve = [&](size_t bytes) -> void* {
    void* p = (void*)w;
    w += (bytes + 255) & ~(size_t)255;
    return p;
  };
  int*      flag      = (int*)     carve(4);
  int*      cnt       = (int*)     carve((size_t)N * 4);
  int*      S         = (int*)     carve(((size_t)N + 1) * 4);
  float*    dinv      = (float*)   carve((size_t)N * 4);
  int*      bsum      = (int*)     carve(1024 * 4);
  unsigned short* W2t = (unsigned short*)carve(48 * 256 * 2);
  int*      rank      = (int*)     carve((size_t)E * 4);
  int*      csr       = (int*)     carve((size_t)E * 4);
  unsigned* pbuf      = (unsigned*)carve((size_t)(KHOPS + 1) * N * 64 * 4); // 11 slabs
  unsigned* hid       = (unsigned*)carve((size_t)N * 64 * 4);   // final hidden bf16
  unsigned short* z1  = (unsigned short*)carve((size_t)N * HID * 2);

  int ntiles = (N + 1023) / 1024;   // 49
  size_t slab = (size_t)N * 64;

  k_detect64<<<1, 256, 0, stream>>>((const unsigned int*)d_in[1], flag);
  k_zero<<<(N + 255) / 256, 256, 0, stream>>>(cnt, N);
  k_count<<<(E + 255) / 256, 256, 0, stream>>>(ei32, ei64, E, N, cnt, rank, flag);
  k_scan_a<<<ntiles, 256, 0, stream>>>(cnt, bsum, N);
  k_scan_mid<<<1, 1024, 0, stream>>>(bsum, S, ntiles, N);
  k_scan_c<<<ntiles, 256, 0, stream>>>(cnt, bsum, S, dinv, N);
  k_fill<<<(E + 255) / 256, 256, 0, stream>>>(ei32, ei64, E, N, S, rank, csr, flag);
  k_init<<<(N * 64 + 255) / 256, 256, 0, stream>>>(x, dinv, pbuf, N * 64);
  k_w2prep<<<48, 256, 0, stream>>>(W2, W2t);

  for (int k = 0; k < KHOPS; ++k) {
    k_prop<<<(N + 3) / 4, 256, 0, stream>>>(
        pbuf + slab * k, pbuf + slab * (k + 1), S, csr, dinv, N);
  }
  k_combine<<<(N * 64 + 255) / 256, 256, 0, stream>>>(pbuf, temp, dinv, hid, N);

  k_gemm1<<<dim3((N + 63) / 64, 2), 256, 0, stream>>>(
      (const unsigned short*)hid, W1, b1, z1, N);
  k_mlp2<<<(N + 63) / 64, 256, 0, stream>>>(z1, W2t, b2, out, N);
}

// Round 5
// 488.907 us; speedup vs baseline: 1.9738x; 1.1780x over previous
//
#include <hip/hip_runtime.h>
#include <hip/hip_bf16.h>

// GPR-GNN forward on MI355X.
// R18: revert R17's k_prop tweaks (no per-dispatch signal; total regressed
// on an anomalous container). k_prop is at its L2-request-throughput
// roofline (~40us/hop, invariant to FETCH 25->86MB across R13/R15/R16).
// This round: fuse k_combine into k_gemm1 (k_gemm1f, BN=256 single pass,
// n0 looped internally, Bs restaged per pass, Zs epilogue reuses the Bs
// region). Eliminates the hid buffer: -12.8MB write, -25.6MB read, -1
// launch. Everything else is the twice-proven R13 structure.

#define NFEAT 128
#define HID   256
#define NCLS  40
#define KHOPS 10

typedef __attribute__((ext_vector_type(8))) short short8;
typedef __attribute__((ext_vector_type(4))) float floatx4;

__device__ __forceinline__ float blo(unsigned g) { return __uint_as_float(g << 16); }
__device__ __forceinline__ float bhi(unsigned g) { return __uint_as_float(g & 0xffff0000u); }
__device__ __forceinline__ unsigned f2bf(float x) {          // RNE bf16 -> low 16
  unsigned u = __float_as_uint(x);
  return (u + 0x7fffu + ((u >> 16) & 1u)) >> 16;
}
__device__ __forceinline__ unsigned bpack(float a, float b) {
  return f2bf(a) | (f2bf(b) << 16);
}

// ---- storage probe: int64 values < 2^31 have all-zero odd 32-bit words ----
__global__ void k_detect64(const unsigned int* __restrict__ raw, int* __restrict__ flag) {
  __shared__ int any;
  int t = threadIdx.x;
  if (t == 0) any = 0;
  __syncthreads();
  if (raw[2 * t + 1] != 0u) any = 1;
  __syncthreads();
  if (t == 0) flag[0] = (any == 0) ? 1 : 0;   // 1 => int64 storage
}

__global__ void k_zero(int* __restrict__ p, int n) {
  int i = blockIdx.x * blockDim.x + threadIdx.x;
  if (i < n) p[i] = 0;
}

// 1 edge/thread; stores the atomic's return as this edge's rank within dst.
__global__ void k_count(const int* __restrict__ ei32, const long long* __restrict__ ei64,
                        int E, int N, int* __restrict__ cnt, int* __restrict__ rank,
                        const int* __restrict__ flag) {
  int e = blockIdx.x * blockDim.x + threadIdx.x;
  if (e >= E) return;
  int dst = flag[0] ? (int)ei64[(size_t)E + e] : ei32[(size_t)E + e];
  if ((unsigned)dst < (unsigned)N) rank[e] = atomicAdd(&cnt[dst], 1);
  else rank[e] = -1;
}

// ---- 3-level parallel exclusive scan (tiles of 1024) ----
__global__ __launch_bounds__(256) void k_scan_a(
    const int* __restrict__ cnt, int* __restrict__ bsum, int n) {
  int t = threadIdx.x;
  int base = blockIdx.x * 1024 + t * 4;
  int s = 0;
  if (base + 3 < n) {
    int4 v = *(const int4*)(cnt + base);
    s = v.x + v.y + v.z + v.w;
  } else {
    #pragma unroll
    for (int j = 0; j < 4; ++j) if (base + j < n) s += cnt[base + j];
  }
  #pragma unroll
  for (int off = 1; off < 64; off <<= 1) s += __shfl_xor(s, off);
  __shared__ int ws[4];
  if ((t & 63) == 0) ws[t >> 6] = s;
  __syncthreads();
  if (t == 0) bsum[blockIdx.x] = ws[0] + ws[1] + ws[2] + ws[3];
}

__global__ void k_scan_mid(int* __restrict__ bsum, int* __restrict__ S,
                           int ntiles, int n) {
  int t = threadIdx.x;
  int lane = t & 63, wid = t >> 6;
  int v = (t < ntiles) ? bsum[t] : 0;
  int x = v;
  #pragma unroll
  for (int off = 1; off < 64; off <<= 1) {
    int u = __shfl_up(x, off);
    if (lane >= off) x += u;
  }
  __shared__ int ws[16];
  if (lane == 63) ws[wid] = x;
  __syncthreads();
  if (wid == 0) {
    int s2 = (lane < 16) ? ws[lane] : 0;
    #pragma unroll
    for (int off = 1; off < 16; off <<= 1) {
      int u = __shfl_up(s2, off);
      if (lane >= off) s2 += u;
    }
    if (lane < 16) ws[lane] = s2;
  }
  __syncthreads();
  int woff = wid ? ws[wid - 1] : 0;
  if (t < ntiles) bsum[t] = x - v + woff;   // exclusive tile offsets
  if (t == 0) S[n] = ws[15];                // grand total sentinel
}

// per-tile scan + apply; also emits dinv (counts are in registers here)
__global__ __launch_bounds__(256) void k_scan_c(
    const int* __restrict__ cnt, const int* __restrict__ bsum,
    int* __restrict__ S, float* __restrict__ dinv, int n) {
  int t = threadIdx.x;
  int base = blockIdx.x * 1024 + t * 4;
  int v[4];
  if (base + 3 < n) {
    int4 q = *(const int4*)(cnt + base);
    v[0] = q.x; v[1] = q.y; v[2] = q.z; v[3] = q.w;
  } else {
    #pragma unroll
    for (int j = 0; j < 4; ++j) v[j] = (base + j < n) ? cnt[base + j] : 0;
  }
  int tsum = v[0] + v[1] + v[2] + v[3];
  int lane = t & 63, wv = t >> 6;
  int x = tsum;
  #pragma unroll
  for (int off = 1; off < 64; off <<= 1) {
    int u = __shfl_up(x, off);
    if (lane >= off) x += u;
  }
  __shared__ int ws[4];
  if (lane == 63) ws[wv] = x;
  __syncthreads();
  int woff = 0;
  #pragma unroll
  for (int j = 0; j < 4; ++j) if (j < wv) woff += ws[j];
  int run = x - tsum + woff + bsum[blockIdx.x];
  #pragma unroll
  for (int j = 0; j < 4; ++j) {
    int idx = base + j;
    if (idx < n) {
      S[idx] = run;
      dinv[idx] = rsqrtf((float)(v[j] + 1));
      run += v[j];
    }
  }
}

// atomic-free fill: position = S[dst] + rank[e]; store src only.
__global__ void k_fill(const int* __restrict__ ei32, const long long* __restrict__ ei64,
                       int E, int N, const int* __restrict__ S,
                       const int* __restrict__ rank, int* __restrict__ csr,
                       const int* __restrict__ flag) {
  int e = blockIdx.x * blockDim.x + threadIdx.x;
  if (e >= E) return;
  int r = rank[e];
  if (r < 0) return;
  int src, dst;
  if (flag[0]) { src = (int)ei64[e]; dst = (int)ei64[(size_t)E + e]; }
  else         { src = ei32[e];      dst = ei32[(size_t)E + e]; }
  if ((unsigned)src >= (unsigned)N) return;
  csr[S[dst] + r] = src;
}

// init: p0 = dinv*x (bf16x2, row-major [node][64])
__global__ void k_init(const float* __restrict__ x, const float* __restrict__ dinv,
                       unsigned* __restrict__ p0, int total64) {
  int i = blockIdx.x * blockDim.x + threadIdx.x;
  if (i >= total64) return;
  float2 xv = ((const float2*)x)[i];
  float di = dinv[i >> 6];
  p0[i] = bpack(di * xv.x, di * xv.y);
}

// One wave per node. lane = e*16+g: 4 edges per dwordx4 gather instruction,
// 16 edges in flight. p buffers absorb the symmetric normalization, so the
// gather weight is 1 (tail mask only); p_new = dinv^2 * (sum + p_self).
// Proven R13 form (497.6us twice); at L2-request-throughput roofline.
__global__ __launch_bounds__(256) void k_prop(
    const unsigned* __restrict__ pin, unsigned* __restrict__ pout,
    const int* __restrict__ S, const int* __restrict__ csr,
    const float* __restrict__ dinv, int N) {
  int wid = __builtin_amdgcn_readfirstlane(threadIdx.x >> 6);
  int lane = threadIdx.x & 63;
  int node = blockIdx.x * 4 + wid;           // uniform (SGPR) per wave
  if (node >= N) return;
  int g = lane & 15;                         // 16B sub-row: uints g*4..g*4+3
  int e = lane >> 4;                         // edge subgroup 0..3
  int s = S[node], en = S[node + 1];
  float acc[8] = {0.f, 0.f, 0.f, 0.f, 0.f, 0.f, 0.f, 0.f};
  for (int p = s; p < en; p += 16) {
    uint4 gd[4];
    float wt[4];
    #pragma unroll
    for (int t = 0; t < 4; ++t) {
      int pj = p + t * 4 + e;
      int sidx = csr[pj < en ? pj : s];      // clamped tail: redundant row, w=0
      wt[t] = (pj < en) ? 1.f : 0.f;
      gd[t] = *(const uint4*)(pin + (size_t)sidx * 64 + g * 4);  // 16B of row
    }
    #pragma unroll
    for (int t = 0; t < 4; ++t) {
      const unsigned* gu = (const unsigned*)&gd[t];
      #pragma unroll
      for (int u = 0; u < 4; ++u) {
        acc[u * 2]     += wt[t] * blo(gu[u]);
        acc[u * 2 + 1] += wt[t] * bhi(gu[u]);
      }
    }
  }
  #pragma unroll
  for (int u = 0; u < 8; ++u) {              // reduce over the 4 edge subgroups
    acc[u] += __shfl_xor(acc[u], 16);
    acc[u] += __shfl_xor(acc[u], 32);
  }
  if (e == 0) {                              // lanes 0-15 own the epilogue
    float di = dinv[node];
    float dd = di * di;
    uint4 gs = *(const uint4*)(pin + (size_t)node * 64 + g * 4);
    const unsigned* su = (const unsigned*)&gs;
    #pragma unroll
    for (int u = 0; u < 4; ++u) {
      acc[u * 2]     += blo(su[u]);          // self term: p[i], weight 1
      acc[u * 2 + 1] += bhi(su[u]);
    }
    uint4 pk;                                // p_new = dinv^2 * (sum + self)
    pk.x = bpack(dd * acc[0], dd * acc[1]);
    pk.y = bpack(dd * acc[2], dd * acc[3]);
    pk.z = bpack(dd * acc[4], dd * acc[5]);
    pk.w = bpack(dd * acc[6], dd * acc[7]);
    *(uint4*)(pout + (size_t)node * 64 + g * 4) = pk;
  }
}

// Fused combine+gemm1: hid tile built in LDS from the 11 p-slabs
// (hid = sum_k temp[k]*p_k / dinv), then hid @ W1 + b1, relu -> z1.
// BN=256 in one block (n0 looped), so the 141MB pbuf read happens ONCE
// and the hid buffer never exists in HBM. Zs epilogue reuses Bs region.
__global__ __launch_bounds__(256) void k_gemm1f(
    const unsigned* __restrict__ pbuf, const float* __restrict__ temp,
    const float* __restrict__ dinv, const float* __restrict__ W1,
    const float* __restrict__ b1, unsigned short* __restrict__ z1, int M) {
  __shared__ unsigned short As[64][136];    // hid tile: m-major, k contig, +8 pad
  __shared__ unsigned short Bs[16][128][8]; // per-pass W1 half; reused as Zs
  int tid = threadIdx.x;
  int m0 = blockIdx.x * 64;
  size_t slab = (size_t)M * 64;
  float tk[KHOPS + 1];
  #pragma unroll
  for (int k = 0; k <= KHOPS; ++k) tk[k] = temp[k];
  // phase A: streaming combine of 11 slabs -> As (bf16)
  for (int idx = tid; idx < 64 * 16; idx += 256) {
    int m = idx >> 4, c = idx & 15;
    int row = m0 + m; if (row >= M) row = M - 1;
    const unsigned* pp = pbuf + (size_t)row * 64 + c * 4;
    float tL[4] = {0.f, 0.f, 0.f, 0.f}, tH[4] = {0.f, 0.f, 0.f, 0.f};
    #pragma unroll
    for (int k = 0; k <= KHOPS; ++k) {
      uint4 v = *(const uint4*)(pp + slab * k);
      const unsigned* vu = (const unsigned*)&v;
      #pragma unroll
      for (int u = 0; u < 4; ++u) {
        tL[u] += tk[k] * blo(vu[u]);
        tH[u] += tk[k] * bhi(vu[u]);
      }
    }
    float inv = 1.f / dinv[row];             // h = p / dinv
    uint4 o;
    o.x = bpack(tL[0] * inv, tH[0] * inv);
    o.y = bpack(tL[1] * inv, tH[1] * inv);
    o.z = bpack(tL[2] * inv, tH[2] * inv);
    o.w = bpack(tL[3] * inv, tH[3] * inv);
    *(uint4*)&As[m][c * 8] = o;
  }
  __syncthreads();
  int lane = tid & 63;
  int q = lane >> 4, r16 = lane & 15;
  int nw = (tid >> 6) * 32;
  #pragma unroll
  for (int pass = 0; pass < 2; ++pass) {
    int n0 = pass * 128;
    if (pass) __syncthreads();               // prior Zs copy-out complete
    for (int idx = tid; idx < 128 * 128; idx += 256) {
      int k = idx >> 7, n = idx & 127;
      Bs[k >> 3][n][k & 7] = (unsigned short)f2bf(W1[(size_t)k * HID + n0 + n]);
    }
    __syncthreads();
    floatx4 acc[4][2] = {};
    #pragma unroll
    for (int step = 0; step < 4; ++step) {
      int k0 = step * 32;
      short8 a[4], b[2];
      #pragma unroll
      for (int i = 0; i < 4; ++i)
        a[i] = *(const short8*)&As[i * 16 + r16][k0 + q * 8];
      #pragma unroll
      for (int j = 0; j < 2; ++j)
        b[j] = *(const short8*)&Bs[step * 4 + q][nw + j * 16 + r16][0];
      #pragma unroll
      for (int i = 0; i < 4; ++i)
        #pragma unroll
        for (int j = 0; j < 2; ++j)
          acc[i][j] = __builtin_amdgcn_mfma_f32_16x16x32_bf16(a[i], b[j], acc[i][j], 0, 0, 0);
    }
    __syncthreads();                         // Bs reads done -> reuse as Zs
    unsigned short* Zs = &Bs[0][0][0];
    #pragma unroll
    for (int j = 0; j < 2; ++j) {
      int n = nw + j * 16 + r16;
      float bias = b1[n0 + n];
      #pragma unroll
      for (int i = 0; i < 4; ++i) {
        #pragma unroll
        for (int r = 0; r < 4; ++r) {
          int m = i * 16 + q * 4 + r;
          float v = fmaxf(acc[i][j][r] + bias, 0.f);
          Zs[m * 136 + n] = (unsigned short)f2bf(v);
        }
      }
    }
    __syncthreads();
    for (int idx = tid; idx < 64 * 16; idx += 256) {
      int m = idx >> 4, c = idx & 15;
      int row = m0 + m;
      if (row < M) {
        uint4 v = *(const uint4*)&Zs[m * 136 + c * 8];
        *(uint4*)(z1 + (size_t)row * HID + n0 + c * 8) = v;
      }
    }
  }
}

// W2 (256x40 f32) -> W2t bf16 [48][256] (n-major, k-contig; n>=40 zero-padded)
__global__ void k_w2prep(const float* __restrict__ W2, unsigned short* __restrict__ W2t) {
  int i = blockIdx.x * blockDim.x + threadIdx.x;
  if (i >= 48 * 256) return;
  int n = i >> 8, k = i & 255;
  W2t[n * 256 + k] = (n < NCLS) ? (unsigned short)f2bf(W2[(size_t)k * NCLS + n]) : 0;
}

// z1 (Mx256 bf16) @ W2t + b2 -> log_softmax -> out f32. LDS-free MFMA.
__global__ __launch_bounds__(256) void k_mlp2(
    const unsigned short* __restrict__ z1, const unsigned short* __restrict__ W2t,
    const float* __restrict__ b2, float* __restrict__ out, int N) {
  int tid = threadIdx.x;
  int lane = tid & 63;
  int wv = tid >> 6;
  int node0 = blockIdx.x * 64 + wv * 16;
  int q = lane >> 4, m = lane & 15;
  int arow = node0 + m; if (arow >= N) arow = N - 1;
  const unsigned short* aptr = z1 + (size_t)arow * HID + q * 8;
  const unsigned short* bptr = W2t + (size_t)m * HID + q * 8;   // + j*16*HID
  floatx4 acc[3] = {};
  #pragma unroll
  for (int step = 0; step < 8; ++step) {     // K = 8 x 32
    short8 a = *(const short8*)(aptr + step * 32);
    #pragma unroll
    for (int j = 0; j < 3; ++j) {
      short8 b = *(const short8*)(bptr + (size_t)j * 16 * HID + step * 32);
      acc[j] = __builtin_amdgcn_mfma_f32_16x16x32_bf16(a, b, acc[j], 0, 0, 0);
    }
  }
  int c = m;                                  // class within tile = col = lane&15
  bool v2 = (c < NCLS - 32);                  // c+32 < 40
  float bb0 = b2[c], bb1 = b2[c + 16];
  float bb2 = v2 ? b2[c + 32] : 0.f;
  #pragma unroll
  for (int r = 0; r < 4; ++r) {
    int node = node0 + q * 4 + r;
    float l0 = acc[0][r] + bb0;
    float l1 = acc[1][r] + bb1;
    float l2 = v2 ? (acc[2][r] + bb2) : -3.4e38f;
    float mx = fmaxf(fmaxf(l0, l1), l2);
    #pragma unroll
    for (int off = 1; off < 16; off <<= 1) mx = fmaxf(mx, __shfl_xor(mx, off));
    float sm = __expf(l0 - mx) + __expf(l1 - mx) + (v2 ? __expf(l2 - mx) : 0.f);
    #pragma unroll
    for (int off = 1; off < 16; off <<= 1) sm += __shfl_xor(sm, off);
    float lse = mx + __logf(sm);
    if (node < N) {
      float* op = out + (size_t)node * NCLS + c;
      op[0] = l0 - lse;
      op[16] = l1 - lse;
      if (v2) op[32] = l2 - lse;
    }
  }
}

extern "C" void kernel_launch(void* const* d_in, const int* in_sizes, int n_in,
                              void* d_out, int out_size, void* d_ws, size_t ws_size,
                              hipStream_t stream) {
  const float*     x    = (const float*)d_in[0];
  const int*       ei32 = (const int*)d_in[1];
  const long long* ei64 = (const long long*)d_in[1];
  const float*     temp = (const float*)d_in[2];
  const float*     W1   = (const float*)d_in[3];
  const float*     b1   = (const float*)d_in[4];
  const float*     W2   = (const float*)d_in[5];
  const float*     b2   = (const float*)d_in[6];
  float* out = (float*)d_out;

  int N = in_sizes[0] / NFEAT;   // 50000
  int E = in_sizes[1] / 2;       // 800000

  // workspace carve
  char* w = (char*)d_ws;
  auto carve = [&](size_t bytes) -> void* {
    void* p = (void*)w;
    w += (bytes + 255) & ~(size_t)255;
    return p;
  };
  int*      flag      = (int*)     carve(4);
  int*      cnt       = (int*)     carve((size_t)N * 4);
  int*      S         = (int*)     carve(((size_t)N + 1) * 4);
  float*    dinv      = (float*)   carve((size_t)N * 4);
  int*      bsum      = (int*)     carve(1024 * 4);
  unsigned short* W2t = (unsigned short*)carve(48 * 256 * 2);
  int*      rank      = (int*)     carve((size_t)E * 4);
  int*      csr       = (int*)     carve((size_t)E * 4);
  unsigned* pbuf      = (unsigned*)carve((size_t)(KHOPS + 1) * N * 64 * 4); // 11 slabs
  unsigned short* z1  = (unsigned short*)carve((size_t)N * HID * 2);

  int ntiles = (N + 1023) / 1024;   // 49
  size_t slab = (size_t)N * 64;

  k_detect64<<<1, 256, 0, stream>>>((const unsigned int*)d_in[1], flag);
  k_zero<<<(N + 255) / 256, 256, 0, stream>>>(cnt, N);
  k_count<<<(E + 255) / 256, 256, 0, stream>>>(ei32, ei64, E, N, cnt, rank, flag);
  k_scan_a<<<ntiles, 256, 0, stream>>>(cnt, bsum, N);
  k_scan_mid<<<1, 1024, 0, stream>>>(bsum, S, ntiles, N);
  k_scan_c<<<ntiles, 256, 0, stream>>>(cnt, bsum, S, dinv, N);
  k_fill<<<(E + 255) / 256, 256, 0, stream>>>(ei32, ei64, E, N, S, rank, csr, flag);
  k_init<<<(N * 64 + 255) / 256, 256, 0, stream>>>(x, dinv, pbuf, N * 64);
  k_w2prep<<<48, 256, 0, stream>>>(W2, W2t);

  for (int k = 0; k < KHOPS; ++k) {
    k_prop<<<(N + 3) / 4, 256, 0, stream>>>(
        pbuf + slab * k, pbuf + slab * (k + 1), S, csr, dinv, N);
  }

  k_gemm1f<<<(N + 63) / 64, 256, 0, stream>>>(
      pbuf, temp, dinv, W1, b1, z1, N);
  k_mlp2<<<(N + 63) / 64, 256, 0, stream>>>(z1, W2t, b2, out, N);
}

// Round 6
// 473.459 us; speedup vs baseline: 2.0382x; 1.0326x over previous
//
#include <hip/hip_runtime.h>
#include <hip/hip_bf16.h>

// GPR-GNN forward on MI355X.
// R19: k_gemm1f's 45us decomposed (counters): 2.9M LDS bank conflicts from
// per-block W1 restaging (scalar b16 writes, 8-way), 21% occupancy (50KB
// LDS), phase-serialized traffic at 3.7TB/s. Fix:
//  (1) precompute W1t bf16 [256][128] once (k_w1prep); drop Bs entirely --
//      B fragments read per-MFMA from global (64KB, L2-broadcast).
//  (2) fuse mlp2 in: z1 tile -> LDS (reusing dead As region), mlp2 MFMA +
//      log_softmax in-block. Kills the z1 HBM round-trip (51.2MB) and a
//      launch. LDS 33.8KB -> 4 blocks/CU, launch_bounds(256,4).
// k_prop untouched: established dual-path roofline ~40us/hop (R13-R17).

#define NFEAT 128
#define HID   256
#define NCLS  40
#define KHOPS 10

typedef __attribute__((ext_vector_type(8))) short short8;
typedef __attribute__((ext_vector_type(4))) float floatx4;

__device__ __forceinline__ float blo(unsigned g) { return __uint_as_float(g << 16); }
__device__ __forceinline__ float bhi(unsigned g) { return __uint_as_float(g & 0xffff0000u); }
__device__ __forceinline__ unsigned f2bf(float x) {          // RNE bf16 -> low 16
  unsigned u = __float_as_uint(x);
  return (u + 0x7fffu + ((u >> 16) & 1u)) >> 16;
}
__device__ __forceinline__ unsigned bpack(float a, float b) {
  return f2bf(a) | (f2bf(b) << 16);
}

// ---- storage probe: int64 values < 2^31 have all-zero odd 32-bit words ----
__global__ void k_detect64(const unsigned int* __restrict__ raw, int* __restrict__ flag) {
  __shared__ int any;
  int t = threadIdx.x;
  if (t == 0) any = 0;
  __syncthreads();
  if (raw[2 * t + 1] != 0u) any = 1;
  __syncthreads();
  if (t == 0) flag[0] = (any == 0) ? 1 : 0;   // 1 => int64 storage
}

__global__ void k_zero(int* __restrict__ p, int n) {
  int i = blockIdx.x * blockDim.x + threadIdx.x;
  if (i < n) p[i] = 0;
}

// 1 edge/thread; stores the atomic's return as this edge's rank within dst.
__global__ void k_count(const int* __restrict__ ei32, const long long* __restrict__ ei64,
                        int E, int N, int* __restrict__ cnt, int* __restrict__ rank,
                        const int* __restrict__ flag) {
  int e = blockIdx.x * blockDim.x + threadIdx.x;
  if (e >= E) return;
  int dst = flag[0] ? (int)ei64[(size_t)E + e] : ei32[(size_t)E + e];
  if ((unsigned)dst < (unsigned)N) rank[e] = atomicAdd(&cnt[dst], 1);
  else rank[e] = -1;
}

// ---- 3-level parallel exclusive scan (tiles of 1024) ----
__global__ __launch_bounds__(256) void k_scan_a(
    const int* __restrict__ cnt, int* __restrict__ bsum, int n) {
  int t = threadIdx.x;
  int base = blockIdx.x * 1024 + t * 4;
  int s = 0;
  if (base + 3 < n) {
    int4 v = *(const int4*)(cnt + base);
    s = v.x + v.y + v.z + v.w;
  } else {
    #pragma unroll
    for (int j = 0; j < 4; ++j) if (base + j < n) s += cnt[base + j];
  }
  #pragma unroll
  for (int off = 1; off < 64; off <<= 1) s += __shfl_xor(s, off);
  __shared__ int ws[4];
  if ((t & 63) == 0) ws[t >> 6] = s;
  __syncthreads();
  if (t == 0) bsum[blockIdx.x] = ws[0] + ws[1] + ws[2] + ws[3];
}

__global__ void k_scan_mid(int* __restrict__ bsum, int* __restrict__ S,
                           int ntiles, int n) {
  int t = threadIdx.x;
  int lane = t & 63, wid = t >> 6;
  int v = (t < ntiles) ? bsum[t] : 0;
  int x = v;
  #pragma unroll
  for (int off = 1; off < 64; off <<= 1) {
    int u = __shfl_up(x, off);
    if (lane >= off) x += u;
  }
  __shared__ int ws[16];
  if (lane == 63) ws[wid] = x;
  __syncthreads();
  if (wid == 0) {
    int s2 = (lane < 16) ? ws[lane] : 0;
    #pragma unroll
    for (int off = 1; off < 16; off <<= 1) {
      int u = __shfl_up(s2, off);
      if (lane >= off) s2 += u;
    }
    if (lane < 16) ws[lane] = s2;
  }
  __syncthreads();
  int woff = wid ? ws[wid - 1] : 0;
  if (t < ntiles) bsum[t] = x - v + woff;   // exclusive tile offsets
  if (t == 0) S[n] = ws[15];                // grand total sentinel
}

// per-tile scan + apply; also emits dinv (counts are in registers here)
__global__ __launch_bounds__(256) void k_scan_c(
    const int* __restrict__ cnt, const int* __restrict__ bsum,
    int* __restrict__ S, float* __restrict__ dinv, int n) {
  int t = threadIdx.x;
  int base = blockIdx.x * 1024 + t * 4;
  int v[4];
  if (base + 3 < n) {
    int4 q = *(const int4*)(cnt + base);
    v[0] = q.x; v[1] = q.y; v[2] = q.z; v[3] = q.w;
  } else {
    #pragma unroll
    for (int j = 0; j < 4; ++j) v[j] = (base + j < n) ? cnt[base + j] : 0;
  }
  int tsum = v[0] + v[1] + v[2] + v[3];
  int lane = t & 63, wv = t >> 6;
  int x = tsum;
  #pragma unroll
  for (int off = 1; off < 64; off <<= 1) {
    int u = __shfl_up(x, off);
    if (lane >= off) x += u;
  }
  __shared__ int ws[4];
  if (lane == 63) ws[wv] = x;
  __syncthreads();
  int woff = 0;
  #pragma unroll
  for (int j = 0; j < 4; ++j) if (j < wv) woff += ws[j];
  int run = x - tsum + woff + bsum[blockIdx.x];
  #pragma unroll
  for (int j = 0; j < 4; ++j) {
    int idx = base + j;
    if (idx < n) {
      S[idx] = run;
      dinv[idx] = rsqrtf((float)(v[j] + 1));
      run += v[j];
    }
  }
}

// atomic-free fill: position = S[dst] + rank[e]; store src only.
__global__ void k_fill(const int* __restrict__ ei32, const long long* __restrict__ ei64,
                       int E, int N, const int* __restrict__ S,
                       const int* __restrict__ rank, int* __restrict__ csr,
                       const int* __restrict__ flag) {
  int e = blockIdx.x * blockDim.x + threadIdx.x;
  if (e >= E) return;
  int r = rank[e];
  if (r < 0) return;
  int src, dst;
  if (flag[0]) { src = (int)ei64[e]; dst = (int)ei64[(size_t)E + e]; }
  else         { src = ei32[e];      dst = ei32[(size_t)E + e]; }
  if ((unsigned)src >= (unsigned)N) return;
  csr[S[dst] + r] = src;
}

// init: p0 = dinv*x (bf16x2, row-major [node][64])
__global__ void k_init(const float* __restrict__ x, const float* __restrict__ dinv,
                       unsigned* __restrict__ p0, int total64) {
  int i = blockIdx.x * blockDim.x + threadIdx.x;
  if (i >= total64) return;
  float2 xv = ((const float2*)x)[i];
  float di = dinv[i >> 6];
  p0[i] = bpack(di * xv.x, di * xv.y);
}

// One wave per node. lane = e*16+g: 4 edges per dwordx4 gather instruction,
// 16 edges in flight. Proven R13 form; at the dual-path gather roofline.
__global__ __launch_bounds__(256) void k_prop(
    const unsigned* __restrict__ pin, unsigned* __restrict__ pout,
    const int* __restrict__ S, const int* __restrict__ csr,
    const float* __restrict__ dinv, int N) {
  int wid = __builtin_amdgcn_readfirstlane(threadIdx.x >> 6);
  int lane = threadIdx.x & 63;
  int node = blockIdx.x * 4 + wid;           // uniform (SGPR) per wave
  if (node >= N) return;
  int g = lane & 15;                         // 16B sub-row: uints g*4..g*4+3
  int e = lane >> 4;                         // edge subgroup 0..3
  int s = S[node], en = S[node + 1];
  float acc[8] = {0.f, 0.f, 0.f, 0.f, 0.f, 0.f, 0.f, 0.f};
  for (int p = s; p < en; p += 16) {
    uint4 gd[4];
    float wt[4];
    #pragma unroll
    for (int t = 0; t < 4; ++t) {
      int pj = p + t * 4 + e;
      int sidx = csr[pj < en ? pj : s];      // clamped tail: redundant row, w=0
      wt[t] = (pj < en) ? 1.f : 0.f;
      gd[t] = *(const uint4*)(pin + (size_t)sidx * 64 + g * 4);  // 16B of row
    }
    #pragma unroll
    for (int t = 0; t < 4; ++t) {
      const unsigned* gu = (const unsigned*)&gd[t];
      #pragma unroll
      for (int u = 0; u < 4; ++u) {
        acc[u * 2]     += wt[t] * blo(gu[u]);
        acc[u * 2 + 1] += wt[t] * bhi(gu[u]);
      }
    }
  }
  #pragma unroll
  for (int u = 0; u < 8; ++u) {              // reduce over the 4 edge subgroups
    acc[u] += __shfl_xor(acc[u], 16);
    acc[u] += __shfl_xor(acc[u], 32);
  }
  if (e == 0) {                              // lanes 0-15 own the epilogue
    float di = dinv[node];
    float dd = di * di;
    uint4 gs = *(const uint4*)(pin + (size_t)node * 64 + g * 4);
    const unsigned* su = (const unsigned*)&gs;
    #pragma unroll
    for (int u = 0; u < 4; ++u) {
      acc[u * 2]     += blo(su[u]);          // self term: p[i], weight 1
      acc[u * 2 + 1] += bhi(su[u]);
    }
    uint4 pk;                                // p_new = dinv^2 * (sum + self)
    pk.x = bpack(dd * acc[0], dd * acc[1]);
    pk.y = bpack(dd * acc[2], dd * acc[3]);
    pk.z = bpack(dd * acc[4], dd * acc[5]);
    pk.w = bpack(dd * acc[6], dd * acc[7]);
    *(uint4*)(pout + (size_t)node * 64 + g * 4) = pk;
  }
}

// W1 (128x256 f32, k-major) -> W1t bf16 [256][128] (n-major, k-contig)
__global__ void k_w1prep(const float* __restrict__ W1, unsigned short* __restrict__ W1t) {
  int i = blockIdx.x * blockDim.x + threadIdx.x;
  if (i >= 256 * 128) return;
  int n = i >> 7, k = i & 127;
  W1t[n * 128 + k] = (unsigned short)f2bf(W1[(size_t)k * HID + n]);
}

// W2 (256x40 f32) -> W2t bf16 [48][256] (n-major, k-contig; n>=40 zero-padded)
__global__ void k_w2prep(const float* __restrict__ W2, unsigned short* __restrict__ W2t) {
  int i = blockIdx.x * blockDim.x + threadIdx.x;
  if (i >= 48 * 256) return;
  int n = i >> 8, k = i & 255;
  W2t[n * 256 + k] = (n < NCLS) ? (unsigned short)f2bf(W2[(size_t)k * NCLS + n]) : 0;
}

// Fully fused tail: combine(11 slabs) -> hid tile (LDS) -> @W1t+b1,relu ->
// z1 tile (LDS, reusing dead hid region) -> @W2t+b2 -> log_softmax -> out.
// No Bs staging (B frags read from L2-resident W1t/W2t per MFMA step).
// LDS: one 64x264-ushort buffer; As view stride 136 (phases A/B), Zs view
// stride 264 (phases C/D). 33.8KB -> 4 blocks/CU at launch_bounds(256,4).
__global__ __launch_bounds__(256, 4) void k_fused(
    const unsigned* __restrict__ pbuf, const float* __restrict__ temp,
    const float* __restrict__ dinv, const unsigned short* __restrict__ W1t,
    const float* __restrict__ b1, const unsigned short* __restrict__ W2t,
    const float* __restrict__ b2, float* __restrict__ out, int M) {
  __shared__ unsigned short sbuf[64 * 264];
  int tid = threadIdx.x;
  int m0 = blockIdx.x * 64;
  size_t slab = (size_t)M * 64;
  float tk[KHOPS + 1];
  #pragma unroll
  for (int k = 0; k <= KHOPS; ++k) tk[k] = temp[k];

  // phase A: streaming combine of 11 slabs -> As (bf16, stride 136)
  for (int idx = tid; idx < 64 * 16; idx += 256) {
    int m = idx >> 4, c = idx & 15;
    int row = m0 + m; if (row >= M) row = M - 1;
    const unsigned* pp = pbuf + (size_t)row * 64 + c * 4;
    float tL[4] = {0.f, 0.f, 0.f, 0.f}, tH[4] = {0.f, 0.f, 0.f, 0.f};
    #pragma unroll
    for (int k = 0; k <= KHOPS; ++k) {
      uint4 v = *(const uint4*)(pp + slab * k);
      const unsigned* vu = (const unsigned*)&v;
      #pragma unroll
      for (int u = 0; u < 4; ++u) {
        tL[u] += tk[k] * blo(vu[u]);
        tH[u] += tk[k] * bhi(vu[u]);
      }
    }
    float inv = 1.f / dinv[row];             // h = p / dinv
    uint4 o;
    o.x = bpack(tL[0] * inv, tH[0] * inv);
    o.y = bpack(tL[1] * inv, tH[1] * inv);
    o.z = bpack(tL[2] * inv, tH[2] * inv);
    o.w = bpack(tL[3] * inv, tH[3] * inv);
    *(uint4*)&sbuf[m * 136 + c * 8] = o;
  }
  __syncthreads();

  int lane = tid & 63;
  int wv = tid >> 6;
  int q = lane >> 4, r16 = lane & 15;

  // phase B: hid @ W1t -> acc[4][4]; wave wv owns cols [wv*64, wv*64+64)
  floatx4 acc[4][4] = {};
  #pragma unroll
  for (int step = 0; step < 4; ++step) {
    int k0 = step * 32;
    short8 a[4], b[4];
    #pragma unroll
    for (int i = 0; i < 4; ++i)
      a[i] = *(const short8*)&sbuf[(i * 16 + r16) * 136 + k0 + q * 8];
    #pragma unroll
    for (int j = 0; j < 4; ++j)
      b[j] = *(const short8*)&W1t[(size_t)(wv * 64 + j * 16 + r16) * 128 + k0 + q * 8];
    #pragma unroll
    for (int i = 0; i < 4; ++i)
      #pragma unroll
      for (int j = 0; j < 4; ++j)
        acc[i][j] = __builtin_amdgcn_mfma_f32_16x16x32_bf16(a[i], b[j], acc[i][j], 0, 0, 0);
  }
  __syncthreads();                           // As dead; buffer becomes Zs

  // phase C: bias+relu -> Zs bf16 (stride 264)
  #pragma unroll
  for (int j = 0; j < 4; ++j) {
    int n = wv * 64 + j * 16 + r16;
    float bias = b1[n];
    #pragma unroll
    for (int i = 0; i < 4; ++i) {
      #pragma unroll
      for (int r = 0; r < 4; ++r) {
        int m = i * 16 + q * 4 + r;
        float v = fmaxf(acc[i][j][r] + bias, 0.f);
        sbuf[m * 264 + n] = (unsigned short)f2bf(v);
      }
    }
  }
  __syncthreads();

  // phase D: z1 @ W2t + b2 -> log_softmax -> out (wave wv: rows wv*16..+15)
  int node0 = m0 + wv * 16;
  int mm = lane & 15;                        // row-within-16 AND class col
  const unsigned short* aL = &sbuf[(wv * 16 + mm) * 264 + q * 8];
  const unsigned short* bptr = W2t + (size_t)mm * HID + q * 8;
  floatx4 acc2[3] = {};
  #pragma unroll
  for (int step = 0; step < 8; ++step) {     // K = 8 x 32
    short8 a = *(const short8*)(aL + step * 32);
    #pragma unroll
    for (int j = 0; j < 3; ++j) {
      short8 b = *(const short8*)(bptr + (size_t)j * 16 * HID + step * 32);
      acc2[j] = __builtin_amdgcn_mfma_f32_16x16x32_bf16(a, b, acc2[j], 0, 0, 0);
    }
  }
  int c = mm;
  bool v2 = (c < NCLS - 32);                 // c+32 < 40
  float bb0 = b2[c], bb1 = b2[c + 16];
  float bb2 = v2 ? b2[c + 32] : 0.f;
  #pragma unroll
  for (int r = 0; r < 4; ++r) {
    int node = node0 + q * 4 + r;
    float l0 = acc2[0][r] + bb0;
    float l1 = acc2[1][r] + bb1;
    float l2 = v2 ? (acc2[2][r] + bb2) : -3.4e38f;
    float mx = fmaxf(fmaxf(l0, l1), l2);
    #pragma unroll
    for (int off = 1; off < 16; off <<= 1) mx = fmaxf(mx, __shfl_xor(mx, off));
    float sm = __expf(l0 - mx) + __expf(l1 - mx) + (v2 ? __expf(l2 - mx) : 0.f);
    #pragma unroll
    for (int off = 1; off < 16; off <<= 1) sm += __shfl_xor(sm, off);
    float lse = mx + __logf(sm);
    if (node < M) {
      float* op = out + (size_t)node * NCLS + c;
      op[0] = l0 - lse;
      op[16] = l1 - lse;
      if (v2) op[32] = l2 - lse;
    }
  }
}

extern "C" void kernel_launch(void* const* d_in, const int* in_sizes, int n_in,
                              void* d_out, int out_size, void* d_ws, size_t ws_size,
                              hipStream_t stream) {
  const float*     x    = (const float*)d_in[0];
  const int*       ei32 = (const int*)d_in[1];
  const long long* ei64 = (const long long*)d_in[1];
  const float*     temp = (const float*)d_in[2];
  const float*     W1   = (const float*)d_in[3];
  const float*     b1   = (const float*)d_in[4];
  const float*     W2   = (const float*)d_in[5];
  const float*     b2   = (const float*)d_in[6];
  float* out = (float*)d_out;

  int N = in_sizes[0] / NFEAT;   // 50000
  int E = in_sizes[1] / 2;       // 800000

  // workspace carve
  char* w = (char*)d_ws;
  auto carve = [&](size_t bytes) -> void* {
    void* p = (void*)w;
    w += (bytes + 255) & ~(size_t)255;
    return p;
  };
  int*      flag      = (int*)     carve(4);
  int*      cnt       = (int*)     carve((size_t)N * 4);
  int*      S         = (int*)     carve(((size_t)N + 1) * 4);
  float*    dinv      = (float*)   carve((size_t)N * 4);
  int*      bsum      = (int*)     carve(1024 * 4);
  unsigned short* W1t = (unsigned short*)carve(256 * 128 * 2);
  unsigned short* W2t = (unsigned short*)carve(48 * 256 * 2);
  int*      rank      = (int*)     carve((size_t)E * 4);
  int*      csr       = (int*)     carve((size_t)E * 4);
  unsigned* pbuf      = (unsigned*)carve((size_t)(KHOPS + 1) * N * 64 * 4); // 11 slabs

  int ntiles = (N + 1023) / 1024;   // 49
  size_t slab = (size_t)N * 64;

  k_detect64<<<1, 256, 0, stream>>>((const unsigned int*)d_in[1], flag);
  k_zero<<<(N + 255) / 256, 256, 0, stream>>>(cnt, N);
  k_count<<<(E + 255) / 256, 256, 0, stream>>>(ei32, ei64, E, N, cnt, rank, flag);
  k_scan_a<<<ntiles, 256, 0, stream>>>(cnt, bsum, N);
  k_scan_mid<<<1, 1024, 0, stream>>>(bsum, S, ntiles, N);
  k_scan_c<<<ntiles, 256, 0, stream>>>(cnt, bsum, S, dinv, N);
  k_fill<<<(E + 255) / 256, 256, 0, stream>>>(ei32, ei64, E, N, S, rank, csr, flag);
  k_init<<<(N * 64 + 255) / 256, 256, 0, stream>>>(x, dinv, pbuf, N * 64);
  k_w1prep<<<128, 256, 0, stream>>>(W1, W1t);
  k_w2prep<<<48, 256, 0, stream>>>(W2, W2t);

  for (int k = 0; k < KHOPS; ++k) {
    k_prop<<<(N + 3) / 4, 256, 0, stream>>>(
        pbuf + slab * k, pbuf + slab * (k + 1), S, csr, dinv, N);
  }

  k_fused<<<(N + 63) / 64, 256, 0, stream>>>(
      pbuf, temp, dinv, W1t, b1, W2t, b2, out, N);
}

// Round 7
// 469.796 us; speedup vs baseline: 2.0541x; 1.0078x over previous
//
#include <hip/hip_runtime.h>
#include <hip/hip_bf16.h>

// GPR-GNN forward on MI355X.
// R20: k_fused was latency-bound in its streaming combine (Occ 23%: grid
// 782 = 3 blocks/CU x 4 waves = 12 waves/CU; 11 indep 16B loads/thread vs
// ~900cy HBM latency; HBM pull 1.9TB/s). Same BM=64 tile, 8 waves/block
// (512 thr) -> 24 waves/CU at unchanged LDS/W1t traffic. Phase B: 8 waves
// x 32 cols (acc[4][2]); phase D: waves 0-3 (unchanged), 4-7 idle.
// k_prop untouched: dual-path gather roofline ~40us/hop (R13-R17).

#define NFEAT 128
#define HID   256
#define NCLS  40
#define KHOPS 10

typedef __attribute__((ext_vector_type(8))) short short8;
typedef __attribute__((ext_vector_type(4))) float floatx4;

__device__ __forceinline__ float blo(unsigned g) { return __uint_as_float(g << 16); }
__device__ __forceinline__ float bhi(unsigned g) { return __uint_as_float(g & 0xffff0000u); }
__device__ __forceinline__ unsigned f2bf(float x) {          // RNE bf16 -> low 16
  unsigned u = __float_as_uint(x);
  return (u + 0x7fffu + ((u >> 16) & 1u)) >> 16;
}
__device__ __forceinline__ unsigned bpack(float a, float b) {
  return f2bf(a) | (f2bf(b) << 16);
}

// ---- storage probe: int64 values < 2^31 have all-zero odd 32-bit words ----
__global__ void k_detect64(const unsigned int* __restrict__ raw, int* __restrict__ flag) {
  __shared__ int any;
  int t = threadIdx.x;
  if (t == 0) any = 0;
  __syncthreads();
  if (raw[2 * t + 1] != 0u) any = 1;
  __syncthreads();
  if (t == 0) flag[0] = (any == 0) ? 1 : 0;   // 1 => int64 storage
}

__global__ void k_zero(int* __restrict__ p, int n) {
  int i = blockIdx.x * blockDim.x + threadIdx.x;
  if (i < n) p[i] = 0;
}

// 1 edge/thread; stores the atomic's return as this edge's rank within dst.
__global__ void k_count(const int* __restrict__ ei32, const long long* __restrict__ ei64,
                        int E, int N, int* __restrict__ cnt, int* __restrict__ rank,
                        const int* __restrict__ flag) {
  int e = blockIdx.x * blockDim.x + threadIdx.x;
  if (e >= E) return;
  int dst = flag[0] ? (int)ei64[(size_t)E + e] : ei32[(size_t)E + e];
  if ((unsigned)dst < (unsigned)N) rank[e] = atomicAdd(&cnt[dst], 1);
  else rank[e] = -1;
}

// ---- 3-level parallel exclusive scan (tiles of 1024) ----
__global__ __launch_bounds__(256) void k_scan_a(
    const int* __restrict__ cnt, int* __restrict__ bsum, int n) {
  int t = threadIdx.x;
  int base = blockIdx.x * 1024 + t * 4;
  int s = 0;
  if (base + 3 < n) {
    int4 v = *(const int4*)(cnt + base);
    s = v.x + v.y + v.z + v.w;
  } else {
    #pragma unroll
    for (int j = 0; j < 4; ++j) if (base + j < n) s += cnt[base + j];
  }
  #pragma unroll
  for (int off = 1; off < 64; off <<= 1) s += __shfl_xor(s, off);
  __shared__ int ws[4];
  if ((t & 63) == 0) ws[t >> 6] = s;
  __syncthreads();
  if (t == 0) bsum[blockIdx.x] = ws[0] + ws[1] + ws[2] + ws[3];
}

__global__ void k_scan_mid(int* __restrict__ bsum, int* __restrict__ S,
                           int ntiles, int n) {
  int t = threadIdx.x;
  int lane = t & 63, wid = t >> 6;
  int v = (t < ntiles) ? bsum[t] : 0;
  int x = v;
  #pragma unroll
  for (int off = 1; off < 64; off <<= 1) {
    int u = __shfl_up(x, off);
    if (lane >= off) x += u;
  }
  __shared__ int ws[16];
  if (lane == 63) ws[wid] = x;
  __syncthreads();
  if (wid == 0) {
    int s2 = (lane < 16) ? ws[lane] : 0;
    #pragma unroll
    for (int off = 1; off < 16; off <<= 1) {
      int u = __shfl_up(s2, off);
      if (lane >= off) s2 += u;
    }
    if (lane < 16) ws[lane] = s2;
  }
  __syncthreads();
  int woff = wid ? ws[wid - 1] : 0;
  if (t < ntiles) bsum[t] = x - v + woff;   // exclusive tile offsets
  if (t == 0) S[n] = ws[15];                // grand total sentinel
}

// per-tile scan + apply; also emits dinv (counts are in registers here)
__global__ __launch_bounds__(256) void k_scan_c(
    const int* __restrict__ cnt, const int* __restrict__ bsum,
    int* __restrict__ S, float* __restrict__ dinv, int n) {
  int t = threadIdx.x;
  int base = blockIdx.x * 1024 + t * 4;
  int v[4];
  if (base + 3 < n) {
    int4 q = *(const int4*)(cnt + base);
    v[0] = q.x; v[1] = q.y; v[2] = q.z; v[3] = q.w;
  } else {
    #pragma unroll
    for (int j = 0; j < 4; ++j) v[j] = (base + j < n) ? cnt[base + j] : 0;
  }
  int tsum = v[0] + v[1] + v[2] + v[3];
  int lane = t & 63, wv = t >> 6;
  int x = tsum;
  #pragma unroll
  for (int off = 1; off < 64; off <<= 1) {
    int u = __shfl_up(x, off);
    if (lane >= off) x += u;
  }
  __shared__ int ws[4];
  if (lane == 63) ws[wv] = x;
  __syncthreads();
  int woff = 0;
  #pragma unroll
  for (int j = 0; j < 4; ++j) if (j < wv) woff += ws[j];
  int run = x - tsum + woff + bsum[blockIdx.x];
  #pragma unroll
  for (int j = 0; j < 4; ++j) {
    int idx = base + j;
    if (idx < n) {
      S[idx] = run;
      dinv[idx] = rsqrtf((float)(v[j] + 1));
      run += v[j];
    }
  }
}

// atomic-free fill: position = S[dst] + rank[e]; store src only.
__global__ void k_fill(const int* __restrict__ ei32, const long long* __restrict__ ei64,
                       int E, int N, const int* __restrict__ S,
                       const int* __restrict__ rank, int* __restrict__ csr,
                       const int* __restrict__ flag) {
  int e = blockIdx.x * blockDim.x + threadIdx.x;
  if (e >= E) return;
  int r = rank[e];
  if (r < 0) return;
  int src, dst;
  if (flag[0]) { src = (int)ei64[e]; dst = (int)ei64[(size_t)E + e]; }
  else         { src = ei32[e];      dst = ei32[(size_t)E + e]; }
  if ((unsigned)src >= (unsigned)N) return;
  csr[S[dst] + r] = src;
}

// init: p0 = dinv*x (bf16x2, row-major [node][64])
__global__ void k_init(const float* __restrict__ x, const float* __restrict__ dinv,
                       unsigned* __restrict__ p0, int total64) {
  int i = blockIdx.x * blockDim.x + threadIdx.x;
  if (i >= total64) return;
  float2 xv = ((const float2*)x)[i];
  float di = dinv[i >> 6];
  p0[i] = bpack(di * xv.x, di * xv.y);
}

// One wave per node. lane = e*16+g: 4 edges per dwordx4 gather instruction,
// 16 edges in flight. Proven R13 form; at the dual-path gather roofline.
__global__ __launch_bounds__(256) void k_prop(
    const unsigned* __restrict__ pin, unsigned* __restrict__ pout,
    const int* __restrict__ S, const int* __restrict__ csr,
    const float* __restrict__ dinv, int N) {
  int wid = __builtin_amdgcn_readfirstlane(threadIdx.x >> 6);
  int lane = threadIdx.x & 63;
  int node = blockIdx.x * 4 + wid;           // uniform (SGPR) per wave
  if (node >= N) return;
  int g = lane & 15;                         // 16B sub-row: uints g*4..g*4+3
  int e = lane >> 4;                         // edge subgroup 0..3
  int s = S[node], en = S[node + 1];
  float acc[8] = {0.f, 0.f, 0.f, 0.f, 0.f, 0.f, 0.f, 0.f};
  for (int p = s; p < en; p += 16) {
    uint4 gd[4];
    float wt[4];
    #pragma unroll
    for (int t = 0; t < 4; ++t) {
      int pj = p + t * 4 + e;
      int sidx = csr[pj < en ? pj : s];      // clamped tail: redundant row, w=0
      wt[t] = (pj < en) ? 1.f : 0.f;
      gd[t] = *(const uint4*)(pin + (size_t)sidx * 64 + g * 4);  // 16B of row
    }
    #pragma unroll
    for (int t = 0; t < 4; ++t) {
      const unsigned* gu = (const unsigned*)&gd[t];
      #pragma unroll
      for (int u = 0; u < 4; ++u) {
        acc[u * 2]     += wt[t] * blo(gu[u]);
        acc[u * 2 + 1] += wt[t] * bhi(gu[u]);
      }
    }
  }
  #pragma unroll
  for (int u = 0; u < 8; ++u) {              // reduce over the 4 edge subgroups
    acc[u] += __shfl_xor(acc[u], 16);
    acc[u] += __shfl_xor(acc[u], 32);
  }
  if (e == 0) {                              // lanes 0-15 own the epilogue
    float di = dinv[node];
    float dd = di * di;
    uint4 gs = *(const uint4*)(pin + (size_t)node * 64 + g * 4);
    const unsigned* su = (const unsigned*)&gs;
    #pragma unroll
    for (int u = 0; u < 4; ++u) {
      acc[u * 2]     += blo(su[u]);          // self term: p[i], weight 1
      acc[u * 2 + 1] += bhi(su[u]);
    }
    uint4 pk;                                // p_new = dinv^2 * (sum + self)
    pk.x = bpack(dd * acc[0], dd * acc[1]);
    pk.y = bpack(dd * acc[2], dd * acc[3]);
    pk.z = bpack(dd * acc[4], dd * acc[5]);
    pk.w = bpack(dd * acc[6], dd * acc[7]);
    *(uint4*)(pout + (size_t)node * 64 + g * 4) = pk;
  }
}

// W1 (128x256 f32, k-major) -> W1t bf16 [256][128] (n-major, k-contig)
__global__ void k_w1prep(const float* __restrict__ W1, unsigned short* __restrict__ W1t) {
  int i = blockIdx.x * blockDim.x + threadIdx.x;
  if (i >= 256 * 128) return;
  int n = i >> 7, k = i & 127;
  W1t[n * 128 + k] = (unsigned short)f2bf(W1[(size_t)k * HID + n]);
}

// W2 (256x40 f32) -> W2t bf16 [48][256] (n-major, k-contig; n>=40 zero-padded)
__global__ void k_w2prep(const float* __restrict__ W2, unsigned short* __restrict__ W2t) {
  int i = blockIdx.x * blockDim.x + threadIdx.x;
  if (i >= 48 * 256) return;
  int n = i >> 8, k = i & 255;
  W2t[n * 256 + k] = (n < NCLS) ? (unsigned short)f2bf(W2[(size_t)k * NCLS + n]) : 0;
}

// Fully fused tail, 512 threads: combine(11 slabs) -> hid tile (LDS) ->
// @W1t+b1,relu -> z1 tile (LDS reuse) -> @W2t+b2 -> log_softmax -> out.
// 8 waves: phase B 32 cols/wave; phase D on waves 0-3. 24 waves/CU at
// 3 blocks/CU hides the phase-A HBM latency that capped R19 at 23% occ.
__global__ __launch_bounds__(512, 2) void k_fused(
    const unsigned* __restrict__ pbuf, const float* __restrict__ temp,
    const float* __restrict__ dinv, const unsigned short* __restrict__ W1t,
    const float* __restrict__ b1, const unsigned short* __restrict__ W2t,
    const float* __restrict__ b2, float* __restrict__ out, int M) {
  __shared__ unsigned short sbuf[64 * 264];
  int tid = threadIdx.x;
  int m0 = blockIdx.x * 64;
  size_t slab = (size_t)M * 64;
  float tk[KHOPS + 1];
  #pragma unroll
  for (int k = 0; k <= KHOPS; ++k) tk[k] = temp[k];

  // phase A: streaming combine of 11 slabs -> As (bf16, stride 136)
  for (int idx = tid; idx < 64 * 16; idx += 512) {
    int m = idx >> 4, c = idx & 15;
    int row = m0 + m; if (row >= M) row = M - 1;
    const unsigned* pp = pbuf + (size_t)row * 64 + c * 4;
    float tL[4] = {0.f, 0.f, 0.f, 0.f}, tH[4] = {0.f, 0.f, 0.f, 0.f};
    #pragma unroll
    for (int k = 0; k <= KHOPS; ++k) {
      uint4 v = *(const uint4*)(pp + slab * k);
      const unsigned* vu = (const unsigned*)&v;
      #pragma unroll
      for (int u = 0; u < 4; ++u) {
        tL[u] += tk[k] * blo(vu[u]);
        tH[u] += tk[k] * bhi(vu[u]);
      }
    }
    float inv = 1.f / dinv[row];             // h = p / dinv
    uint4 o;
    o.x = bpack(tL[0] * inv, tH[0] * inv);
    o.y = bpack(tL[1] * inv, tH[1] * inv);
    o.z = bpack(tL[2] * inv, tH[2] * inv);
    o.w = bpack(tL[3] * inv, tH[3] * inv);
    *(uint4*)&sbuf[m * 136 + c * 8] = o;
  }
  __syncthreads();

  int lane = tid & 63;
  int wv = tid >> 6;                         // 0..7
  int q = lane >> 4, r16 = lane & 15;

  // phase B: hid @ W1t -> acc[4][2]; wave wv owns cols [wv*32, wv*32+32)
  floatx4 acc[4][2] = {};
  #pragma unroll
  for (int step = 0; step < 4; ++step) {
    int k0 = step * 32;
    short8 a[4], b[2];
    #pragma unroll
    for (int i = 0; i < 4; ++i)
      a[i] = *(const short8*)&sbuf[(i * 16 + r16) * 136 + k0 + q * 8];
    #pragma unroll
    for (int j = 0; j < 2; ++j)
      b[j] = *(const short8*)&W1t[(size_t)(wv * 32 + j * 16 + r16) * 128 + k0 + q * 8];
    #pragma unroll
    for (int i = 0; i < 4; ++i)
      #pragma unroll
      for (int j = 0; j < 2; ++j)
        acc[i][j] = __builtin_amdgcn_mfma_f32_16x16x32_bf16(a[i], b[j], acc[i][j], 0, 0, 0);
  }
  __syncthreads();                           // As dead; buffer becomes Zs

  // phase C: bias+relu -> Zs bf16 (stride 264)
  #pragma unroll
  for (int j = 0; j < 2; ++j) {
    int n = wv * 32 + j * 16 + r16;
    float bias = b1[n];
    #pragma unroll
    for (int i = 0; i < 4; ++i) {
      #pragma unroll
      for (int r = 0; r < 4; ++r) {
        int m = i * 16 + q * 4 + r;
        float v = fmaxf(acc[i][j][r] + bias, 0.f);
        sbuf[m * 264 + n] = (unsigned short)f2bf(v);
      }
    }
  }
  __syncthreads();

  // phase D: z1 @ W2t + b2 -> log_softmax -> out (waves 0-3: 16 rows each)
  if (wv < 4) {
    int node0 = m0 + wv * 16;
    int mm = lane & 15;                      // row-within-16 AND class col
    const unsigned short* aL = &sbuf[(wv * 16 + mm) * 264 + q * 8];
    const unsigned short* bptr = W2t + (size_t)mm * HID + q * 8;
    floatx4 acc2[3] = {};
    #pragma unroll
    for (int step = 0; step < 8; ++step) {   // K = 8 x 32
      short8 a = *(const short8*)(aL + step * 32);
      #pragma unroll
      for (int j = 0; j < 3; ++j) {
        short8 b = *(const short8*)(bptr + (size_t)j * 16 * HID + step * 32);
        acc2[j] = __builtin_amdgcn_mfma_f32_16x16x32_bf16(a, b, acc2[j], 0, 0, 0);
      }
    }
    int c = mm;
    bool v2 = (c < NCLS - 32);               // c+32 < 40
    float bb0 = b2[c], bb1 = b2[c + 16];
    float bb2 = v2 ? b2[c + 32] : 0.f;
    #pragma unroll
    for (int r = 0; r < 4; ++r) {
      int node = node0 + q * 4 + r;
      float l0 = acc2[0][r] + bb0;
      float l1 = acc2[1][r] + bb1;
      float l2 = v2 ? (acc2[2][r] + bb2) : -3.4e38f;
      float mx = fmaxf(fmaxf(l0, l1), l2);
      #pragma unroll
      for (int off = 1; off < 16; off <<= 1) mx = fmaxf(mx, __shfl_xor(mx, off));
      float sm = __expf(l0 - mx) + __expf(l1 - mx) + (v2 ? __expf(l2 - mx) : 0.f);
      #pragma unroll
      for (int off = 1; off < 16; off <<= 1) sm += __shfl_xor(sm, off);
      float lse = mx + __logf(sm);
      if (node < M) {
        float* op = out + (size_t)node * NCLS + c;
        op[0] = l0 - lse;
        op[16] = l1 - lse;
        if (v2) op[32] = l2 - lse;
      }
    }
  }
}

extern "C" void kernel_launch(void* const* d_in, const int* in_sizes, int n_in,
                              void* d_out, int out_size, void* d_ws, size_t ws_size,
                              hipStream_t stream) {
  const float*     x    = (const float*)d_in[0];
  const int*       ei32 = (const int*)d_in[1];
  const long long* ei64 = (const long long*)d_in[1];
  const float*     temp = (const float*)d_in[2];
  const float*     W1   = (const float*)d_in[3];
  const float*     b1   = (const float*)d_in[4];
  const float*     W2   = (const float*)d_in[5];
  const float*     b2   = (const float*)d_in[6];
  float* out = (float*)d_out;

  int N = in_sizes[0] / NFEAT;   // 50000
  int E = in_sizes[1] / 2;       // 800000

  // workspace carve
  char* w = (char*)d_ws;
  auto carve = [&](size_t bytes) -> void* {
    void* p = (void*)w;
    w += (bytes + 255) & ~(size_t)255;
    return p;
  };
  int*      flag      = (int*)     carve(4);
  int*      cnt       = (int*)     carve((size_t)N * 4);
  int*      S         = (int*)     carve(((size_t)N + 1) * 4);
  float*    dinv      = (float*)   carve((size_t)N * 4);
  int*      bsum      = (int*)     carve(1024 * 4);
  unsigned short* W1t = (unsigned short*)carve(256 * 128 * 2);
  unsigned short* W2t = (unsigned short*)carve(48 * 256 * 2);
  int*      rank      = (int*)     carve((size_t)E * 4);
  int*      csr       = (int*)     carve((size_t)E * 4);
  unsigned* pbuf      = (unsigned*)carve((size_t)(KHOPS + 1) * N * 64 * 4); // 11 slabs

  int ntiles = (N + 1023) / 1024;   // 49
  size_t slab = (size_t)N * 64;

  k_detect64<<<1, 256, 0, stream>>>((const unsigned int*)d_in[1], flag);
  k_zero<<<(N + 255) / 256, 256, 0, stream>>>(cnt, N);
  k_count<<<(E + 255) / 256, 256, 0, stream>>>(ei32, ei64, E, N, cnt, rank, flag);
  k_scan_a<<<ntiles, 256, 0, stream>>>(cnt, bsum, N);
  k_scan_mid<<<1, 1024, 0, stream>>>(bsum, S, ntiles, N);
  k_scan_c<<<ntiles, 256, 0, stream>>>(cnt, bsum, S, dinv, N);
  k_fill<<<(E + 255) / 256, 256, 0, stream>>>(ei32, ei64, E, N, S, rank, csr, flag);
  k_init<<<(N * 64 + 255) / 256, 256, 0, stream>>>(x, dinv, pbuf, N * 64);
  k_w1prep<<<128, 256, 0, stream>>>(W1, W1t);
  k_w2prep<<<48, 256, 0, stream>>>(W2, W2t);

  for (int k = 0; k < KHOPS; ++k) {
    k_prop<<<(N + 3) / 4, 256, 0, stream>>>(
        pbuf + slab * k, pbuf + slab * (k + 1), S, csr, dinv, N);
  }

  k_fused<<<(N + 63) / 64, 512, 0, stream>>>(
      pbuf, temp, dinv, W1t, b1, W2t, b2, out, N);
}